// Round 1
// baseline (1153.366 us; speedup 1.0000x reference)
//
#include <hip/hip_runtime.h>
#include <math.h>

#define NEG_SLOPE 0.2f

// ---------------------------------------------------------------------------
// CSR build: degree -> scan -> scatter (graph shared by both GAT layers)
// ---------------------------------------------------------------------------
__global__ void k_degree(const int* __restrict__ ei, int E, int n, int* __restrict__ deg)
{
    int e = blockIdx.x * blockDim.x + threadIdx.x;
    int etot = E + n;
    if (e < etot) {
        int dst = (e < E) ? ei[E + e] : (e - E);   // self-loops appended
        atomicAdd(&deg[dst], 1);
    }
}

#define SCAN_BLK 1024
__global__ void k_scan1(const int* __restrict__ deg, int* __restrict__ scanned,
                        int* __restrict__ sums, int n)
{
    __shared__ int sh[SCAN_BLK];
    int base = blockIdx.x * SCAN_BLK;
    int t = threadIdx.x;
    int v = (base + t < n) ? deg[base + t] : 0;
    sh[t] = v;
    __syncthreads();
    // Hillis-Steele inclusive scan
    for (int off = 1; off < SCAN_BLK; off <<= 1) {
        int x = (t >= off) ? sh[t - off] : 0;
        __syncthreads();
        sh[t] += x;
        __syncthreads();
    }
    if (base + t < n) scanned[base + t] = sh[t];
    if (t == SCAN_BLK - 1) sums[blockIdx.x] = sh[t];
}

__global__ void k_scan2(int* __restrict__ sums, int nb)
{
    if (threadIdx.x == 0 && blockIdx.x == 0) {
        int run = 0;
        for (int i = 0; i < nb; ++i) { int v = sums[i]; sums[i] = run; run += v; }
    }
}

__global__ void k_scan3(const int* __restrict__ scanned, const int* __restrict__ sums,
                        const int* __restrict__ deg, int* __restrict__ indptr,
                        int* __restrict__ cursor, int n)
{
    int i = blockIdx.x * blockDim.x + threadIdx.x;
    if (i < n) {
        int incl = scanned[i] + sums[i / SCAN_BLK];
        indptr[i + 1] = incl;
        cursor[i] = incl - deg[i];
        if (i == 0) indptr[0] = 0;
    }
}

__global__ void k_scatter(const int* __restrict__ ei, int E, int n,
                          int* __restrict__ cursor,
                          int* __restrict__ csr_src, int* __restrict__ csr_dst)
{
    int e = blockIdx.x * blockDim.x + threadIdx.x;
    int etot = E + n;
    if (e < etot) {
        int src, dst;
        if (e < E) { src = ei[e]; dst = ei[E + e]; }
        else       { src = dst = e - E; }
        int pos = atomicAdd(&cursor[dst], 1);
        csr_src[pos] = src;
        csr_dst[pos] = dst;
    }
}

// ---------------------------------------------------------------------------
// fp32 tiled GEMM: C[M,N] = A[M,K] @ B[K,N] (+bias). K must be multiple of 16,
// N multiple of 4 (true for 256/128/40). 64x64 tile, 256 thr, 4x4 microtile.
// ---------------------------------------------------------------------------
__global__ __launch_bounds__(256) void k_gemm(
    const float* __restrict__ A, const float* __restrict__ B,
    const float* __restrict__ bias, float* __restrict__ C,
    int M, int N, int K)
{
    __shared__ float As[16][65];  // [k][m], +1 pad
    __shared__ float Bs[16][65];  // [k][n]
    const int tid = threadIdx.x;
    const int bm = blockIdx.y * 64;
    const int bn = blockIdx.x * 64;
    const int tx = tid & 15;
    const int ty = tid >> 4;
    float acc[4][4] = {};

    for (int k0 = 0; k0 < K; k0 += 16) {
        {   // A tile: 64 rows x 16 k, float4 along k
            int r  = tid >> 2;
            int kk = (tid & 3) * 4;
            int gr = bm + r;
            float4 v = make_float4(0.f, 0.f, 0.f, 0.f);
            if (gr < M) v = *reinterpret_cast<const float4*>(&A[(size_t)gr * K + k0 + kk]);
            As[kk + 0][r] = v.x; As[kk + 1][r] = v.y;
            As[kk + 2][r] = v.z; As[kk + 3][r] = v.w;
        }
        {   // B tile: 16 k x 64 cols, float4 along n
            int kk = tid >> 4;
            int cb = (tid & 15) * 4;
            int gc = bn + cb;
            const float* bp = &B[(size_t)(k0 + kk) * N + gc];
            float4 v = make_float4(0.f, 0.f, 0.f, 0.f);
            if (gc + 3 < N) {
                v = *reinterpret_cast<const float4*>(bp);
            } else {
                if (gc + 0 < N) v.x = bp[0];
                if (gc + 1 < N) v.y = bp[1];
                if (gc + 2 < N) v.z = bp[2];
            }
            Bs[kk][cb + 0] = v.x; Bs[kk][cb + 1] = v.y;
            Bs[kk][cb + 2] = v.z; Bs[kk][cb + 3] = v.w;
        }
        __syncthreads();
        #pragma unroll
        for (int kk = 0; kk < 16; ++kk) {
            float a[4], b[4];
            #pragma unroll
            for (int i = 0; i < 4; ++i) a[i] = As[kk][ty * 4 + i];
            #pragma unroll
            for (int j = 0; j < 4; ++j) b[j] = Bs[kk][tx * 4 + j];
            #pragma unroll
            for (int i = 0; i < 4; ++i)
                #pragma unroll
                for (int j = 0; j < 4; ++j)
                    acc[i][j] += a[i] * b[j];
        }
        __syncthreads();
    }

    #pragma unroll
    for (int i = 0; i < 4; ++i) {
        int gr = bm + ty * 4 + i;
        if (gr >= M) continue;
        #pragma unroll
        for (int j = 0; j < 4; ++j) {
            int gc = bn + tx * 4 + j;
            if (gc >= N) continue;
            float v = acc[i][j];
            if (bias) v += bias[gc];
            C[(size_t)gr * N + gc] = v;
        }
    }
}

// ---------------------------------------------------------------------------
// Edge logits: one wave per edge. logit = sum_c att[c]*lrelu(xl[src][c]+xr[dst][c])
// ---------------------------------------------------------------------------
template<int VEC>
__global__ __launch_bounds__(256) void k_edge_logits(
    const float* __restrict__ xl, const float* __restrict__ xr,
    const int* __restrict__ csr_src, const int* __restrict__ csr_dst,
    const float* __restrict__ att, float* __restrict__ logits, int ecount)
{
    const int C = VEC * 64;
    int w = (int)((blockIdx.x * 256 + threadIdx.x) >> 6);
    int lane = threadIdx.x & 63;
    if (w >= ecount) return;
    int src = csr_src[w], dst = csr_dst[w];
    size_t lo = (size_t)src * C + lane * VEC;
    size_t ro = (size_t)dst * C + lane * VEC;
    float acc = 0.f;
    if constexpr (VEC == 4) {
        float4 a = *reinterpret_cast<const float4*>(att + lane * 4);
        float4 l = *reinterpret_cast<const float4*>(xl + lo);
        float4 r = *reinterpret_cast<const float4*>(xr + ro);
        float s;
        s = l.x + r.x; s = s > 0.f ? s : NEG_SLOPE * s; acc += a.x * s;
        s = l.y + r.y; s = s > 0.f ? s : NEG_SLOPE * s; acc += a.y * s;
        s = l.z + r.z; s = s > 0.f ? s : NEG_SLOPE * s; acc += a.z * s;
        s = l.w + r.w; s = s > 0.f ? s : NEG_SLOPE * s; acc += a.w * s;
    } else {
        float2 a = *reinterpret_cast<const float2*>(att + lane * 2);
        float2 l = *reinterpret_cast<const float2*>(xl + lo);
        float2 r = *reinterpret_cast<const float2*>(xr + ro);
        float s;
        s = l.x + r.x; s = s > 0.f ? s : NEG_SLOPE * s; acc += a.x * s;
        s = l.y + r.y; s = s > 0.f ? s : NEG_SLOPE * s; acc += a.y * s;
    }
    #pragma unroll
    for (int off = 32; off; off >>= 1) acc += __shfl_down(acc, off);
    if (lane == 0) logits[w] = acc;
}

// ---------------------------------------------------------------------------
// Per-node fused segment softmax + weighted aggregation (+bias+relu).
// One block of C threads per node; CSR order, no atomics.
// ---------------------------------------------------------------------------
template<int C>
__global__ __launch_bounds__(C) void k_aggregate(
    const float* __restrict__ xl, const float* __restrict__ logits,
    const int* __restrict__ csr_src, const int* __restrict__ indptr,
    const float* __restrict__ bias, float* __restrict__ out, int do_relu)
{
    const int tid = threadIdx.x;
    const int i = blockIdx.x;
    const int beg = indptr[i], end = indptr[i + 1];
    __shared__ float red[C / 64];

    // segment max
    float m = -3.4e38f;
    for (int k = beg + tid; k < end; k += C) m = fmaxf(m, logits[k]);
    #pragma unroll
    for (int off = 32; off; off >>= 1) m = fmaxf(m, __shfl_xor(m, off));
    if ((tid & 63) == 0) red[tid >> 6] = m;
    __syncthreads();
    float mm = red[0];
    #pragma unroll
    for (int w = 1; w < C / 64; ++w) mm = fmaxf(mm, red[w]);
    __syncthreads();

    // segment sum of exp
    float s = 0.f;
    for (int k = beg + tid; k < end; k += C) s += __expf(logits[k] - mm);
    #pragma unroll
    for (int off = 32; off; off >>= 1) s += __shfl_xor(s, off);
    if ((tid & 63) == 0) red[tid >> 6] = s;
    __syncthreads();
    float denom = 0.f;
    #pragma unroll
    for (int w = 0; w < C / 64; ++w) denom += red[w];
    float inv = 1.0f / denom;

    // weighted aggregation: coalesced 1KB row gathers
    float acc = 0.f;
    for (int k = beg; k < end; ++k) {
        float wgt = __expf(logits[k] - mm) * inv;
        acc += wgt * xl[(size_t)csr_src[k] * C + tid];
    }
    float v = acc + bias[tid];
    if (do_relu) v = fmaxf(v, 0.f);
    out[(size_t)i * C + tid] = v;
}

// ---------------------------------------------------------------------------
extern "C" void kernel_launch(void* const* d_in, const int* in_sizes, int n_in,
                              void* d_out, int out_size, void* d_ws, size_t ws_size,
                              hipStream_t stream)
{
    const float* x    = (const float*)d_in[0];
    const int*   ei   = (const int*)d_in[1];
    const float* W1l  = (const float*)d_in[2];
    const float* W1r  = (const float*)d_in[3];
    const float* att1 = (const float*)d_in[4];
    const float* b1   = (const float*)d_in[5];
    const float* W2l  = (const float*)d_in[6];
    const float* W2r  = (const float*)d_in[7];
    const float* att2 = (const float*)d_in[8];
    const float* b2   = (const float*)d_in[9];
    const float* Wc   = (const float*)d_in[10];
    const float* bc   = (const float*)d_in[11];

    const int h1 = in_sizes[4];        // 256
    const int h2 = in_sizes[8];        // 128
    const int c  = in_sizes[11];       // 40
    const int f  = in_sizes[2] / h1;   // 128
    const int n  = in_sizes[0] / f;    // 50000
    const int E  = in_sizes[1] / 2;    // 800000
    const int Etot = E + n;

    char* p = (char*)d_ws;
    auto alloc = [&](size_t bytes) -> char* {
        char* r = p; p += (bytes + 255) & ~(size_t)255; return r;
    };
    float* xl1     = (float*)alloc((size_t)n * h1 * 4);
    float* xr1     = (float*)alloc((size_t)n * h1 * 4);
    float* hb      = (float*)alloc((size_t)n * h1 * 4);
    float* logits  = (float*)alloc((size_t)Etot * 4);
    int*   csr_src = (int*)alloc((size_t)Etot * 4);
    int*   csr_dst = (int*)alloc((size_t)Etot * 4);
    int*   indptr  = (int*)alloc((size_t)(n + 1) * 4);
    int*   cursor  = (int*)alloc((size_t)n * 4);
    int*   deg     = (int*)alloc((size_t)n * 4);
    int*   scanned = (int*)alloc((size_t)n * 4);
    int*   sums    = (int*)alloc(4096);

    const int tb = 256;

    // ---- CSR build (once; shared by both layers) ----
    hipMemsetAsync(deg, 0, (size_t)n * 4, stream);
    k_degree<<<(Etot + tb - 1) / tb, tb, 0, stream>>>(ei, E, n, deg);
    int nb = (n + SCAN_BLK - 1) / SCAN_BLK;
    k_scan1<<<nb, SCAN_BLK, 0, stream>>>(deg, scanned, sums, n);
    k_scan2<<<1, 64, 0, stream>>>(sums, nb);
    k_scan3<<<(n + tb - 1) / tb, tb, 0, stream>>>(scanned, sums, deg, indptr, cursor, n);
    k_scatter<<<(Etot + tb - 1) / tb, tb, 0, stream>>>(ei, E, n, cursor, csr_src, csr_dst);

    // ---- Layer 1 ----
    dim3 g1((h1 + 63) / 64, (n + 63) / 64);
    k_gemm<<<g1, 256, 0, stream>>>(x, W1l, nullptr, xl1, n, h1, f);
    k_gemm<<<g1, 256, 0, stream>>>(x, W1r, nullptr, xr1, n, h1, f);
    k_edge_logits<4><<<(Etot + 3) / 4, 256, 0, stream>>>(xl1, xr1, csr_src, csr_dst, att1, logits, Etot);
    k_aggregate<256><<<n, 256, 0, stream>>>(xl1, logits, csr_src, indptr, b1, hb, 1);

    // ---- Layer 2 (alias xl2/xr2 onto xl1/xr1; h2 result back into hb after reads done) ----
    float* xl2 = xl1;
    float* xr2 = xr1;
    dim3 g2((h2 + 63) / 64, (n + 63) / 64);
    k_gemm<<<g2, 256, 0, stream>>>(hb, W2l, nullptr, xl2, n, h2, h1);
    k_gemm<<<g2, 256, 0, stream>>>(hb, W2r, nullptr, xr2, n, h2, h1);
    k_edge_logits<2><<<(Etot + 3) / 4, 256, 0, stream>>>(xl2, xr2, csr_src, csr_dst, att2, logits, Etot);
    k_aggregate<128><<<n, 128, 0, stream>>>(xl2, logits, csr_src, indptr, b2, hb, 1);

    // ---- Classifier ----
    dim3 g3((c + 63) / 64, (n + 63) / 64);
    k_gemm<<<g3, 256, 0, stream>>>(hb, Wc, bc, (float*)d_out, n, c, h2);
}

// Round 2
// 897.961 us; speedup vs baseline: 1.2844x; 1.2844x over previous
//
#include <hip/hip_runtime.h>
#include <math.h>

#define NEG_SLOPE 0.2f

// ---------------------------------------------------------------------------
// CSR build: degree -> scan -> scatter (graph shared by both GAT layers)
// ---------------------------------------------------------------------------
__global__ void k_degree(const int* __restrict__ ei, int E, int n, int* __restrict__ deg)
{
    int e = blockIdx.x * blockDim.x + threadIdx.x;
    int etot = E + n;
    if (e < etot) {
        int dst = (e < E) ? ei[E + e] : (e - E);   // self-loops appended
        atomicAdd(&deg[dst], 1);
    }
}

#define SCAN_BLK 1024
__global__ void k_scan1(const int* __restrict__ deg, int* __restrict__ scanned,
                        int* __restrict__ sums, int n)
{
    __shared__ int sh[SCAN_BLK];
    int base = blockIdx.x * SCAN_BLK;
    int t = threadIdx.x;
    int v = (base + t < n) ? deg[base + t] : 0;
    sh[t] = v;
    __syncthreads();
    for (int off = 1; off < SCAN_BLK; off <<= 1) {
        int x = (t >= off) ? sh[t - off] : 0;
        __syncthreads();
        sh[t] += x;
        __syncthreads();
    }
    if (base + t < n) scanned[base + t] = sh[t];
    if (t == SCAN_BLK - 1) sums[blockIdx.x] = sh[t];
}

__global__ void k_scan2(int* __restrict__ sums, int nb)
{
    if (threadIdx.x == 0 && blockIdx.x == 0) {
        int run = 0;
        for (int i = 0; i < nb; ++i) { int v = sums[i]; sums[i] = run; run += v; }
    }
}

__global__ void k_scan3(const int* __restrict__ scanned, const int* __restrict__ sums,
                        const int* __restrict__ deg, int* __restrict__ indptr,
                        int* __restrict__ cursor, int n)
{
    int i = blockIdx.x * blockDim.x + threadIdx.x;
    if (i < n) {
        int incl = scanned[i] + sums[i / SCAN_BLK];
        indptr[i + 1] = incl;
        cursor[i] = incl - deg[i];
        if (i == 0) indptr[0] = 0;
    }
}

__global__ void k_scatter(const int* __restrict__ ei, int E, int n,
                          int* __restrict__ cursor, int* __restrict__ csr_src)
{
    int e = blockIdx.x * blockDim.x + threadIdx.x;
    int etot = E + n;
    if (e < etot) {
        int src, dst;
        if (e < E) { src = ei[e]; dst = ei[E + e]; }
        else       { src = dst = e - E; }
        int pos = atomicAdd(&cursor[dst], 1);
        csr_src[pos] = src;
    }
}

// ---------------------------------------------------------------------------
// fp32 tiled GEMM: C[M,N] = A[M,K] @ B[K,N] (+bias). K mult of 16, N mult of 4.
// ---------------------------------------------------------------------------
__global__ __launch_bounds__(256) void k_gemm(
    const float* __restrict__ A, const float* __restrict__ B,
    const float* __restrict__ bias, float* __restrict__ C,
    int M, int N, int K)
{
    __shared__ float As[16][65];
    __shared__ float Bs[16][65];
    const int tid = threadIdx.x;
    const int bm = blockIdx.y * 64;
    const int bn = blockIdx.x * 64;
    const int tx = tid & 15;
    const int ty = tid >> 4;
    float acc[4][4] = {};

    for (int k0 = 0; k0 < K; k0 += 16) {
        {
            int r  = tid >> 2;
            int kk = (tid & 3) * 4;
            int gr = bm + r;
            float4 v = make_float4(0.f, 0.f, 0.f, 0.f);
            if (gr < M) v = *reinterpret_cast<const float4*>(&A[(size_t)gr * K + k0 + kk]);
            As[kk + 0][r] = v.x; As[kk + 1][r] = v.y;
            As[kk + 2][r] = v.z; As[kk + 3][r] = v.w;
        }
        {
            int kk = tid >> 4;
            int cb = (tid & 15) * 4;
            int gc = bn + cb;
            const float* bp = &B[(size_t)(k0 + kk) * N + gc];
            float4 v = make_float4(0.f, 0.f, 0.f, 0.f);
            if (gc + 3 < N) {
                v = *reinterpret_cast<const float4*>(bp);
            } else {
                if (gc + 0 < N) v.x = bp[0];
                if (gc + 1 < N) v.y = bp[1];
                if (gc + 2 < N) v.z = bp[2];
            }
            Bs[kk][cb + 0] = v.x; Bs[kk][cb + 1] = v.y;
            Bs[kk][cb + 2] = v.z; Bs[kk][cb + 3] = v.w;
        }
        __syncthreads();
        #pragma unroll
        for (int kk = 0; kk < 16; ++kk) {
            float a[4], b[4];
            #pragma unroll
            for (int i = 0; i < 4; ++i) a[i] = As[kk][ty * 4 + i];
            #pragma unroll
            for (int j = 0; j < 4; ++j) b[j] = Bs[kk][tx * 4 + j];
            #pragma unroll
            for (int i = 0; i < 4; ++i)
                #pragma unroll
                for (int j = 0; j < 4; ++j)
                    acc[i][j] += a[i] * b[j];
        }
        __syncthreads();
    }

    #pragma unroll
    for (int i = 0; i < 4; ++i) {
        int gr = bm + ty * 4 + i;
        if (gr >= M) continue;
        #pragma unroll
        for (int j = 0; j < 4; ++j) {
            int gc = bn + tx * 4 + j;
            if (gc >= N) continue;
            float v = acc[i][j];
            if (bias) v += bias[gc];
            C[(size_t)gr * N + gc] = v;
        }
    }
}

// ---------------------------------------------------------------------------
// Fused edge-logits + segment-softmax + aggregation. One WAVE per node.
// Online softmax over 64-edge chunks; logits kept in registers (lane j holds
// edge j's logit); no LDS, no block sync. Pass B re-reads rows (L1/L2 hot).
// ---------------------------------------------------------------------------
template<int VEC>   // channels C = VEC*64
__global__ __launch_bounds__(256) void k_fused(
    const float* __restrict__ xl, const float* __restrict__ xr,
    const int* __restrict__ csr_src, const int* __restrict__ indptr,
    const float* __restrict__ att, const float* __restrict__ bias,
    float* __restrict__ out, int n, int do_relu)
{
    const int C = VEC * 64;
    const int lane = threadIdx.x & 63;
    const int node = blockIdx.x * 4 + (threadIdx.x >> 6);
    if (node >= n) return;
    const int beg = indptr[node], end = indptr[node + 1];

    float attr[VEC], xri[VEC];
    if constexpr (VEC == 4) {
        float4 a = *reinterpret_cast<const float4*>(att + lane * 4);
        attr[0] = a.x; attr[1] = a.y; attr[2] = a.z; attr[3] = a.w;
        float4 r = *reinterpret_cast<const float4*>(xr + (size_t)node * C + lane * 4);
        xri[0] = r.x; xri[1] = r.y; xri[2] = r.z; xri[3] = r.w;
    } else {
        float2 a = *reinterpret_cast<const float2*>(att + lane * 2);
        attr[0] = a.x; attr[1] = a.y;
        float2 r = *reinterpret_cast<const float2*>(xr + (size_t)node * C + lane * 2);
        xri[0] = r.x; xri[1] = r.y;
    }

    float m = -3.4e38f, s = 0.f;
    float acc[VEC] = {};

    for (int base = beg; base < end; base += 64) {
        const int len = (end - base < 64) ? (end - base) : 64;
        int csr = (base + lane < end) ? csr_src[base + lane] : 0;

        // ---- pass A: logits for this chunk; lane j keeps edge j's logit ----
        float mylogit = 0.f;
        float cmax = -3.4e38f;
        for (int j = 0; j < len; ++j) {
            int src = __shfl(csr, j);
            const float* rp = xl + (size_t)src * C + lane * VEC;
            float p = 0.f;
            if constexpr (VEC == 4) {
                float4 v = *reinterpret_cast<const float4*>(rp);
                float t;
                t = v.x + xri[0]; t = t > 0.f ? t : NEG_SLOPE * t; p += attr[0] * t;
                t = v.y + xri[1]; t = t > 0.f ? t : NEG_SLOPE * t; p += attr[1] * t;
                t = v.z + xri[2]; t = t > 0.f ? t : NEG_SLOPE * t; p += attr[2] * t;
                t = v.w + xri[3]; t = t > 0.f ? t : NEG_SLOPE * t; p += attr[3] * t;
            } else {
                float2 v = *reinterpret_cast<const float2*>(rp);
                float t;
                t = v.x + xri[0]; t = t > 0.f ? t : NEG_SLOPE * t; p += attr[0] * t;
                t = v.y + xri[1]; t = t > 0.f ? t : NEG_SLOPE * t; p += attr[1] * t;
            }
            #pragma unroll
            for (int off = 1; off < 64; off <<= 1) p += __shfl_xor(p, off);
            if (lane == j) mylogit = p;
            cmax = fmaxf(cmax, p);
        }

        // ---- online-softmax rescale ----
        float newm = fmaxf(m, cmax);
        float scale = __expf(m - newm);   // first chunk: exp(-inf)=0, s/acc are 0
        s *= scale;
        #pragma unroll
        for (int v = 0; v < VEC; ++v) acc[v] *= scale;
        m = newm;

        // ---- pass B: weights + accumulate (rows are cache-hot) ----
        for (int j = 0; j < len; ++j) {
            float w = __expf(__shfl(mylogit, j) - m);
            s += w;
            int src = __shfl(csr, j);
            const float* rp = xl + (size_t)src * C + lane * VEC;
            if constexpr (VEC == 4) {
                float4 v = *reinterpret_cast<const float4*>(rp);
                acc[0] += w * v.x; acc[1] += w * v.y;
                acc[2] += w * v.z; acc[3] += w * v.w;
            } else {
                float2 v = *reinterpret_cast<const float2*>(rp);
                acc[0] += w * v.x; acc[1] += w * v.y;
            }
        }
    }

    float inv = 1.f / s;
    #pragma unroll
    for (int v = 0; v < VEC; ++v) {
        float o = acc[v] * inv + bias[lane * VEC + v];
        if (do_relu) o = fmaxf(o, 0.f);
        out[(size_t)node * C + lane * VEC + v] = o;
    }
}

// ---------------------------------------------------------------------------
extern "C" void kernel_launch(void* const* d_in, const int* in_sizes, int n_in,
                              void* d_out, int out_size, void* d_ws, size_t ws_size,
                              hipStream_t stream)
{
    const float* x    = (const float*)d_in[0];
    const int*   ei   = (const int*)d_in[1];
    const float* W1l  = (const float*)d_in[2];
    const float* W1r  = (const float*)d_in[3];
    const float* att1 = (const float*)d_in[4];
    const float* b1   = (const float*)d_in[5];
    const float* W2l  = (const float*)d_in[6];
    const float* W2r  = (const float*)d_in[7];
    const float* att2 = (const float*)d_in[8];
    const float* b2   = (const float*)d_in[9];
    const float* Wc   = (const float*)d_in[10];
    const float* bc   = (const float*)d_in[11];

    const int h1 = in_sizes[4];        // 256
    const int h2 = in_sizes[8];        // 128
    const int c  = in_sizes[11];       // 40
    const int f  = in_sizes[2] / h1;   // 128
    const int n  = in_sizes[0] / f;    // 50000
    const int E  = in_sizes[1] / 2;    // 800000
    const int Etot = E + n;

    char* p = (char*)d_ws;
    auto alloc = [&](size_t bytes) -> char* {
        char* r = p; p += (bytes + 255) & ~(size_t)255; return r;
    };
    float* xl1     = (float*)alloc((size_t)n * h1 * 4);
    float* xr1     = (float*)alloc((size_t)n * h1 * 4);
    float* hb      = (float*)alloc((size_t)n * h1 * 4);
    int*   csr_src = (int*)alloc((size_t)Etot * 4);
    int*   indptr  = (int*)alloc((size_t)(n + 1) * 4);
    int*   cursor  = (int*)alloc((size_t)n * 4);
    int*   deg     = (int*)alloc((size_t)n * 4);
    int*   scanned = (int*)alloc((size_t)n * 4);
    int*   sums    = (int*)alloc(4096);

    const int tb = 256;

    // ---- CSR build (once; shared by both layers) ----
    hipMemsetAsync(deg, 0, (size_t)n * 4, stream);
    k_degree<<<(Etot + tb - 1) / tb, tb, 0, stream>>>(ei, E, n, deg);
    int nb = (n + SCAN_BLK - 1) / SCAN_BLK;
    k_scan1<<<nb, SCAN_BLK, 0, stream>>>(deg, scanned, sums, n);
    k_scan2<<<1, 64, 0, stream>>>(sums, nb);
    k_scan3<<<(n + tb - 1) / tb, tb, 0, stream>>>(scanned, sums, deg, indptr, cursor, n);
    k_scatter<<<(Etot + tb - 1) / tb, tb, 0, stream>>>(ei, E, n, cursor, csr_src);

    // ---- Layer 1 ----
    dim3 g1((h1 + 63) / 64, (n + 63) / 64);
    k_gemm<<<g1, 256, 0, stream>>>(x, W1l, nullptr, xl1, n, h1, f);
    k_gemm<<<g1, 256, 0, stream>>>(x, W1r, nullptr, xr1, n, h1, f);
    k_fused<4><<<(n + 3) / 4, 256, 0, stream>>>(xl1, xr1, csr_src, indptr,
                                                att1, b1, hb, n, 1);

    // ---- Layer 2 ----
    float* xl2 = xl1;
    float* xr2 = xr1;
    dim3 g2((h2 + 63) / 64, (n + 63) / 64);
    k_gemm<<<g2, 256, 0, stream>>>(hb, W2l, nullptr, xl2, n, h2, h1);
    k_gemm<<<g2, 256, 0, stream>>>(hb, W2r, nullptr, xr2, n, h2, h1);
    k_fused<2><<<(n + 3) / 4, 256, 0, stream>>>(xl2, xr2, csr_src, indptr,
                                                att2, b2, hb, n, 1);

    // ---- Classifier ----
    dim3 g3((c + 63) / 64, (n + 63) / 64);
    k_gemm<<<g3, 256, 0, stream>>>(hb, Wc, bc, (float*)d_out, n, c, h2);
}

// Round 10
// 734.111 us; speedup vs baseline: 1.5711x; 1.2232x over previous
//
#include <hip/hip_runtime.h>
#include <math.h>

#define NEG_SLOPE 0.2f

typedef __attribute__((ext_vector_type(8))) short short8;   // 8 bf16
typedef __attribute__((ext_vector_type(4))) float f32x4;

// Split fp32 into bf16 hi (truncate) + bf16 lo (RNE of exact remainder).
__device__ __forceinline__ void split2(float f, short& hi, short& lo)
{
    unsigned u  = __float_as_uint(f);
    unsigned hu = u & 0xffff0000u;
    hi = (short)(hu >> 16);
    float r = f - __uint_as_float(hu);           // exact
    unsigned ru = __float_as_uint(r);
    unsigned rnd = ru + 0x7fffu + ((ru >> 16) & 1u);
    lo = (short)(rnd >> 16);
}

// ---------------------------------------------------------------------------
// CSR build (unchanged)
// ---------------------------------------------------------------------------
__global__ void k_degree(const int* __restrict__ ei, int E, int n, int* __restrict__ deg)
{
    int e = blockIdx.x * blockDim.x + threadIdx.x;
    int etot = E + n;
    if (e < etot) {
        int dst = (e < E) ? ei[E + e] : (e - E);
        atomicAdd(&deg[dst], 1);
    }
}

#define SCAN_BLK 1024
__global__ void k_scan1(const int* __restrict__ deg, int* __restrict__ scanned,
                        int* __restrict__ sums, int n)
{
    __shared__ int sh[SCAN_BLK];
    int base = blockIdx.x * SCAN_BLK;
    int t = threadIdx.x;
    int v = (base + t < n) ? deg[base + t] : 0;
    sh[t] = v;
    __syncthreads();
    for (int off = 1; off < SCAN_BLK; off <<= 1) {
        int x = (t >= off) ? sh[t - off] : 0;
        __syncthreads();
        sh[t] += x;
        __syncthreads();
    }
    if (base + t < n) scanned[base + t] = sh[t];
    if (t == SCAN_BLK - 1) sums[blockIdx.x] = sh[t];
}

__global__ void k_scan2(int* __restrict__ sums, int nb)
{
    if (threadIdx.x == 0 && blockIdx.x == 0) {
        int run = 0;
        for (int i = 0; i < nb; ++i) { int v = sums[i]; sums[i] = run; run += v; }
    }
}

__global__ void k_scan3(const int* __restrict__ scanned, const int* __restrict__ sums,
                        const int* __restrict__ deg, int* __restrict__ indptr,
                        int* __restrict__ cursor, int n)
{
    int i = blockIdx.x * blockDim.x + threadIdx.x;
    if (i < n) {
        int incl = scanned[i] + sums[i / SCAN_BLK];
        indptr[i + 1] = incl;
        cursor[i] = incl - deg[i];
        if (i == 0) indptr[0] = 0;
    }
}

__global__ void k_scatter(const int* __restrict__ ei, int E, int n,
                          int* __restrict__ cursor, int* __restrict__ csr_src)
{
    int e = blockIdx.x * blockDim.x + threadIdx.x;
    int etot = E + n;
    if (e < etot) {
        int src, dst;
        if (e < E) { src = ei[e]; dst = ei[E + e]; }
        else       { src = dst = e - E; }
        int pos = atomicAdd(&cursor[dst], 1);
        csr_src[pos] = src;
    }
}

// ---------------------------------------------------------------------------
// Conversions: A[M][K] f32 -> A2[M][2K] bf16 [hi|lo];  W cols -> Bt[N][2K]
// ---------------------------------------------------------------------------
__global__ void k_split_a(const float* __restrict__ X, short* __restrict__ A2,
                          long total4, int K)
{
    long t = (long)blockIdx.x * blockDim.x + threadIdx.x;
    if (t >= total4) return;
    long i = t * 4;
    int row = (int)(i / K);
    int k   = (int)(i % K);
    float4 v = *reinterpret_cast<const float4*>(X + i);
    short4 hi, lo;
    split2(v.x, hi.x, lo.x); split2(v.y, hi.y, lo.y);
    split2(v.z, hi.z, lo.z); split2(v.w, hi.w, lo.w);
    short* base = A2 + (size_t)row * 2 * K + k;
    *reinterpret_cast<short4*>(base)     = hi;
    *reinterpret_cast<short4*>(base + K) = lo;
}

__global__ void k_split_bt(const float* __restrict__ Wa, const float* __restrict__ Wb,
                           int Na, int Nb, int K, short* __restrict__ Bt)
{
    int idx = blockIdx.x * blockDim.x + threadIdx.x;
    int N = Na + Nb;
    if (idx >= N * K) return;
    int j = idx / K, k = idx % K;
    float v = (j < Na) ? Wa[(size_t)k * Na + j] : Wb[(size_t)k * Nb + (j - Na)];
    short hi, lo;
    split2(v, hi, lo);
    Bt[(size_t)j * 2 * K + k]     = hi;
    Bt[(size_t)j * 2 * K + K + k] = lo;
}

// ---------------------------------------------------------------------------
// Split-bf16 MFMA GEMM: C[M][N] = A.B (+bias), A2=[M][2K] bf16, Bt=[N][2K] bf16.
// BM=128, BN in {128,64}; 256 thr = 4 waves (2x2); 16x16x32 bf16 MFMA;
// 3 MFMA per k-chunk: hi*hi + hi*lo + lo*hi. LDS rows padded to 144B.
// ---------------------------------------------------------------------------
template<int BN>
__global__ __launch_bounds__(256) void k_mfma(
    const short* __restrict__ A2, const short* __restrict__ Bt,
    const float* __restrict__ bias, float* __restrict__ C,
    int M, int N, int K)
{
    constexpr int NI = BN / 32;            // n-frags per wave
    __shared__ __align__(16) char lds[(128 + BN) * 144];
    char* As = lds;
    char* Bs = lds + 128 * 144;

    const int tid  = threadIdx.x;
    const int lane = tid & 63;
    const int wid  = tid >> 6;
    const int wr   = wid >> 1;             // 0..1
    const int wc   = wid & 1;              // 0..1
    const int bm   = blockIdx.y * 128;
    const int bn   = blockIdx.x * BN;
    const int K2   = 2 * K;

    f32x4 acc[4][NI] = {};

    const int lrow  = lane & 15;
    const int lslot = (lane >> 4) * 16;

    for (int k0 = 0; k0 < K; k0 += 32) {
        // ---- stage A (128 rows) + B (BN rows): hi chunk (64B) + lo chunk (64B) per row
        for (int slot = tid; slot < 1024 + BN * 8; slot += 256) {
            bool isA = slot < 1024;
            int s0  = isA ? slot : slot - 1024;
            int row = s0 >> 3, s = s0 & 7;
            int grow = (isA ? bm : bn) + row;
            int gk = k0 + ((s & 3) << 3) + ((s >= 4) ? K : 0);
            uint4 v = make_uint4(0u, 0u, 0u, 0u);
            if (isA ? (grow < M) : (grow < N))
                v = *reinterpret_cast<const uint4*>((isA ? A2 : Bt) + (size_t)grow * K2 + gk);
            *reinterpret_cast<uint4*>((isA ? As : Bs) + row * 144 + s * 16) = v;
        }
        __syncthreads();

        // ---- fragments
        short8 ah[4], al[4], bh[NI], bl[NI];
        #pragma unroll
        for (int mi = 0; mi < 4; ++mi) {
            const char* p = As + (wr * 64 + mi * 16 + lrow) * 144 + lslot;
            ah[mi] = *reinterpret_cast<const short8*>(p);
            al[mi] = *reinterpret_cast<const short8*>(p + 64);
        }
        #pragma unroll
        for (int ni = 0; ni < NI; ++ni) {
            const char* p = Bs + (wc * (BN / 2) + ni * 16 + lrow) * 144 + lslot;
            bh[ni] = *reinterpret_cast<const short8*>(p);
            bl[ni] = *reinterpret_cast<const short8*>(p + 64);
        }

        #pragma unroll
        for (int mi = 0; mi < 4; ++mi)
            #pragma unroll
            for (int ni = 0; ni < NI; ++ni) {
                acc[mi][ni] = __builtin_amdgcn_mfma_f32_16x16x32_bf16(ah[mi], bh[ni], acc[mi][ni], 0, 0, 0);
                acc[mi][ni] = __builtin_amdgcn_mfma_f32_16x16x32_bf16(ah[mi], bl[ni], acc[mi][ni], 0, 0, 0);
                acc[mi][ni] = __builtin_amdgcn_mfma_f32_16x16x32_bf16(al[mi], bh[ni], acc[mi][ni], 0, 0, 0);
            }
        __syncthreads();
    }

    // ---- epilogue: D row=(lane>>4)*4+q, col=lane&15 (m89-verified layout)
    #pragma unroll
    for (int mi = 0; mi < 4; ++mi)
        #pragma unroll
        for (int ni = 0; ni < NI; ++ni) {
            int row0 = bm + wr * 64 + mi * 16 + (lane >> 4) * 4;
            int col  = bn + wc * (BN / 2) + ni * 16 + (lane & 15);
            if (col >= N) continue;
            float badd = bias ? bias[col] : 0.f;
            #pragma unroll
            for (int q = 0; q < 4; ++q) {
                int row = row0 + q;
                if (row < M) C[(size_t)row * N + col] = acc[mi][ni][q] + badd;
            }
        }
}

// ---------------------------------------------------------------------------
// Fused edge-logits + segment-softmax + aggregation (wave per node).
// Reads xl/xr fp32 with row stride ldx; writes split-bf16 [hi(C)|lo(C)] rows.
// ---------------------------------------------------------------------------
template<int VEC>   // channels C = VEC*64
__global__ __launch_bounds__(256) void k_fused(
    const float* __restrict__ xl, const float* __restrict__ xr, int ldx,
    const int* __restrict__ csr_src, const int* __restrict__ indptr,
    const float* __restrict__ att, const float* __restrict__ bias,
    short* __restrict__ outs, int n)
{
    const int C = VEC * 64;
    const int lane = threadIdx.x & 63;
    const int node = blockIdx.x * 4 + (threadIdx.x >> 6);
    if (node >= n) return;
    const int beg = indptr[node], end = indptr[node + 1];

    float attr[VEC], xri[VEC];
    if constexpr (VEC == 4) {
        float4 a = *reinterpret_cast<const float4*>(att + lane * 4);
        attr[0] = a.x; attr[1] = a.y; attr[2] = a.z; attr[3] = a.w;
        float4 r = *reinterpret_cast<const float4*>(xr + (size_t)node * ldx + lane * 4);
        xri[0] = r.x; xri[1] = r.y; xri[2] = r.z; xri[3] = r.w;
    } else {
        float2 a = *reinterpret_cast<const float2*>(att + lane * 2);
        attr[0] = a.x; attr[1] = a.y;
        float2 r = *reinterpret_cast<const float2*>(xr + (size_t)node * ldx + lane * 2);
        xri[0] = r.x; xri[1] = r.y;
    }

    float m = -3.4e38f, s = 0.f;
    float acc[VEC] = {};

    for (int base = beg; base < end; base += 64) {
        const int len = (end - base < 64) ? (end - base) : 64;
        int csr = (base + lane < end) ? csr_src[base + lane] : 0;

        float mylogit = 0.f;
        float cmax = -3.4e38f;
        for (int j = 0; j < len; ++j) {
            int src = __shfl(csr, j);
            const float* rp = xl + (size_t)src * ldx + lane * VEC;
            float p = 0.f;
            if constexpr (VEC == 4) {
                float4 v = *reinterpret_cast<const float4*>(rp);
                float t;
                t = v.x + xri[0]; t = t > 0.f ? t : NEG_SLOPE * t; p += attr[0] * t;
                t = v.y + xri[1]; t = t > 0.f ? t : NEG_SLOPE * t; p += attr[1] * t;
                t = v.z + xri[2]; t = t > 0.f ? t : NEG_SLOPE * t; p += attr[2] * t;
                t = v.w + xri[3]; t = t > 0.f ? t : NEG_SLOPE * t; p += attr[3] * t;
            } else {
                float2 v = *reinterpret_cast<const float2*>(rp);
                float t;
                t = v.x + xri[0]; t = t > 0.f ? t : NEG_SLOPE * t; p += attr[0] * t;
                t = v.y + xri[1]; t = t > 0.f ? t : NEG_SLOPE * t; p += attr[1] * t;
            }
            #pragma unroll
            for (int off = 1; off < 64; off <<= 1) p += __shfl_xor(p, off);
            if (lane == j) mylogit = p;
            cmax = fmaxf(cmax, p);
        }

        float newm = fmaxf(m, cmax);
        float scale = __expf(m - newm);
        s *= scale;
        #pragma unroll
        for (int v = 0; v < VEC; ++v) acc[v] *= scale;
        m = newm;

        for (int j = 0; j < len; ++j) {
            float w = __expf(__shfl(mylogit, j) - m);
            s += w;
            int src = __shfl(csr, j);
            const float* rp = xl + (size_t)src * ldx + lane * VEC;
            if constexpr (VEC == 4) {
                float4 v = *reinterpret_cast<const float4*>(rp);
                acc[0] += w * v.x; acc[1] += w * v.y;
                acc[2] += w * v.z; acc[3] += w * v.w;
            } else {
                float2 v = *reinterpret_cast<const float2*>(rp);
                acc[0] += w * v.x; acc[1] += w * v.y;
            }
        }
    }

    float inv = 1.f / s;
    #pragma unroll
    for (int v = 0; v < VEC; ++v) {
        float o = fmaxf(acc[v] * inv + bias[lane * VEC + v], 0.f);  // relu
        short hi, lo;
        split2(o, hi, lo);
        int c = lane * VEC + v;
        outs[(size_t)node * 2 * C + c]     = hi;
        outs[(size_t)node * 2 * C + C + c] = lo;
    }
}

// ---------------------------------------------------------------------------
extern "C" void kernel_launch(void* const* d_in, const int* in_sizes, int n_in,
                              void* d_out, int out_size, void* d_ws, size_t ws_size,
                              hipStream_t stream)
{
    const float* x    = (const float*)d_in[0];
    const int*   ei   = (const int*)d_in[1];
    const float* W1l  = (const float*)d_in[2];
    const float* W1r  = (const float*)d_in[3];
    const float* att1 = (const float*)d_in[4];
    const float* b1   = (const float*)d_in[5];
    const float* W2l  = (const float*)d_in[6];
    const float* W2r  = (const float*)d_in[7];
    const float* att2 = (const float*)d_in[8];
    const float* b2   = (const float*)d_in[9];
    const float* Wc   = (const float*)d_in[10];
    const float* bc   = (const float*)d_in[11];

    const int h1 = in_sizes[4];        // 256
    const int h2 = in_sizes[8];        // 128
    const int c  = in_sizes[11];       // 40
    const int f  = in_sizes[2] / h1;   // 128
    const int n  = in_sizes[0] / f;    // 50000
    const int E  = in_sizes[1] / 2;    // 800000
    const int Etot = E + n;

    char* p = (char*)d_ws;
    auto alloc = [&](size_t bytes) -> char* {
        char* r = p; p += (bytes + 255) & ~(size_t)255; return r;
    };
    // 102.4 MB: xlr1 [n][2*h1] f32; later reused as xlr2 [n][2*h2] f32
    float* xlr1    = (float*)alloc((size_t)n * 2 * h1 * 4);
    // 51.2 MB: hsplit1 [n][2*h1] bf16
    short* hsplit1 = (short*)alloc((size_t)n * 2 * h1 * 2);
    // 25.6 MB: a2x [n][2*f] bf16; later reused as hsplit2 [n][2*h2] bf16
    short* a2x     = (short*)alloc((size_t)n * 2 * f * 2);
    short* bt1     = (short*)alloc((size_t)(2 * h1) * (2 * f) * 2);
    short* bt2     = (short*)alloc((size_t)(2 * h2) * (2 * h1) * 2);
    short* btc     = (short*)alloc((size_t)c * (2 * h2) * 2);
    int*   csr_src = (int*)alloc((size_t)Etot * 4);
    int*   indptr  = (int*)alloc((size_t)(n + 1) * 4);
    int*   cursor  = (int*)alloc((size_t)n * 4);
    int*   deg     = (int*)alloc((size_t)n * 4);
    int*   scanned = (int*)alloc((size_t)n * 4);
    int*   sums    = (int*)alloc(4096);

    float* xlr2    = xlr1;     // alias (xlr1 dead after fused1)
    short* hsplit2 = a2x;      // alias (a2x dead after L1 GEMM)

    const int tb = 256;

    // ---- conversions ----
    long total4 = (long)n * f / 4;
    k_split_a<<<(int)((total4 + tb - 1) / tb), tb, 0, stream>>>(x, a2x, total4, f);
    k_split_bt<<<(2 * h1 * f + tb - 1) / tb, tb, 0, stream>>>(W1l, W1r, h1, h1, f, bt1);
    k_split_bt<<<(2 * h2 * h1 + tb - 1) / tb, tb, 0, stream>>>(W2l, W2r, h2, h2, h1, bt2);
    k_split_bt<<<(c * h2 + tb - 1) / tb, tb, 0, stream>>>(Wc, nullptr, c, 0, h2, btc);

    // ---- CSR build ----
    hipMemsetAsync(deg, 0, (size_t)n * 4, stream);
    k_degree<<<(Etot + tb - 1) / tb, tb, 0, stream>>>(ei, E, n, deg);
    int nb = (n + SCAN_BLK - 1) / SCAN_BLK;
    k_scan1<<<nb, SCAN_BLK, 0, stream>>>(deg, scanned, sums, n);
    k_scan2<<<1, 64, 0, stream>>>(sums, nb);
    k_scan3<<<(n + tb - 1) / tb, tb, 0, stream>>>(scanned, sums, deg, indptr, cursor, n);
    k_scatter<<<(Etot + tb - 1) / tb, tb, 0, stream>>>(ei, E, n, cursor, csr_src);

    const int gy = (n + 127) / 128;

    // ---- Layer 1: xlr1 = x @ [W1l|W1r] ----
    k_mfma<128><<<dim3((2 * h1 + 127) / 128, gy), 256, 0, stream>>>(
        a2x, bt1, nullptr, xlr1, n, 2 * h1, f);
    k_fused<4><<<(n + 3) / 4, 256, 0, stream>>>(
        xlr1, xlr1 + h1, 2 * h1, csr_src, indptr, att1, b1, hsplit1, n);

    // ---- Layer 2: xlr2 = h1act @ [W2l|W2r] ----
    k_mfma<128><<<dim3((2 * h2 + 127) / 128, gy), 256, 0, stream>>>(
        hsplit1, bt2, nullptr, xlr2, n, 2 * h2, h1);
    k_fused<2><<<(n + 3) / 4, 256, 0, stream>>>(
        xlr2, xlr2 + h2, 2 * h2, csr_src, indptr, att2, b2, hsplit2, n);

    // ---- Classifier: d_out = h2act @ Wc + bc ----
    k_mfma<64><<<dim3((c + 63) / 64, gy), 256, 0, stream>>>(
        hsplit2, btc, bc, (float*)d_out, n, c, h2);
}

// Round 12
// 480.370 us; speedup vs baseline: 2.4010x; 1.5282x over previous
//
#include <hip/hip_runtime.h>
#include <math.h>

#define NEG_SLOPE 0.2f

typedef __attribute__((ext_vector_type(8))) short short8;   // 8 bf16
typedef __attribute__((ext_vector_type(4))) float f32x4;

// Split fp32 into bf16 hi (truncate) + bf16 lo (RNE of exact remainder).
__device__ __forceinline__ void split2(float f, short& hi, short& lo)
{
    unsigned u  = __float_as_uint(f);
    unsigned hu = u & 0xffff0000u;
    hi = (short)(hu >> 16);
    float r = f - __uint_as_float(hu);           // exact
    unsigned ru = __float_as_uint(r);
    unsigned rnd = ru + 0x7fffu + ((ru >> 16) & 1u);
    lo = (short)(rnd >> 16);
}

__device__ __forceinline__ unsigned short bf16rne(float f)
{
    unsigned u = __float_as_uint(f);
    unsigned rnd = u + 0x7fffu + ((u >> 16) & 1u);
    return (unsigned short)(rnd >> 16);
}

__device__ __forceinline__ float bf2f(unsigned short h)
{
    return __uint_as_float(((unsigned)h) << 16);
}

// ---------------------------------------------------------------------------
// CSR build (unchanged)
// ---------------------------------------------------------------------------
__global__ void k_degree(const int* __restrict__ ei, int E, int n, int* __restrict__ deg)
{
    int e = blockIdx.x * blockDim.x + threadIdx.x;
    int etot = E + n;
    if (e < etot) {
        int dst = (e < E) ? ei[E + e] : (e - E);
        atomicAdd(&deg[dst], 1);
    }
}

#define SCAN_BLK 1024
__global__ void k_scan1(const int* __restrict__ deg, int* __restrict__ scanned,
                        int* __restrict__ sums, int n)
{
    __shared__ int sh[SCAN_BLK];
    int base = blockIdx.x * SCAN_BLK;
    int t = threadIdx.x;
    int v = (base + t < n) ? deg[base + t] : 0;
    sh[t] = v;
    __syncthreads();
    for (int off = 1; off < SCAN_BLK; off <<= 1) {
        int x = (t >= off) ? sh[t - off] : 0;
        __syncthreads();
        sh[t] += x;
        __syncthreads();
    }
    if (base + t < n) scanned[base + t] = sh[t];
    if (t == SCAN_BLK - 1) sums[blockIdx.x] = sh[t];
}

__global__ void k_scan2(int* __restrict__ sums, int nb)
{
    if (threadIdx.x == 0 && blockIdx.x == 0) {
        int run = 0;
        for (int i = 0; i < nb; ++i) { int v = sums[i]; sums[i] = run; run += v; }
    }
}

__global__ void k_scan3(const int* __restrict__ scanned, const int* __restrict__ sums,
                        const int* __restrict__ deg, int* __restrict__ indptr,
                        int* __restrict__ cursor, int n)
{
    int i = blockIdx.x * blockDim.x + threadIdx.x;
    if (i < n) {
        int incl = scanned[i] + sums[i / SCAN_BLK];
        indptr[i + 1] = incl;
        cursor[i] = incl - deg[i];
        if (i == 0) indptr[0] = 0;
    }
}

__global__ void k_scatter(const int* __restrict__ ei, int E, int n,
                          int* __restrict__ cursor, int* __restrict__ csr_src)
{
    int e = blockIdx.x * blockDim.x + threadIdx.x;
    int etot = E + n;
    if (e < etot) {
        int src, dst;
        if (e < E) { src = ei[e]; dst = ei[E + e]; }
        else       { src = dst = e - E; }
        int pos = atomicAdd(&cursor[dst], 1);
        csr_src[pos] = src;
    }
}

// ---------------------------------------------------------------------------
// Conversions -> interleaved split layout: row = [hi32|lo32][hi32|lo32]...
// element k: idx = row*2K + ((k>>5)<<6) + (k&31); lo at idx+32.
// Each k-chunk of 32 is a contiguous 128B block (matches GEMM staging).
// ---------------------------------------------------------------------------
__global__ void k_split_a(const float* __restrict__ X, short* __restrict__ A2,
                          long total4, int K)
{
    long t = (long)blockIdx.x * blockDim.x + threadIdx.x;
    if (t >= total4) return;
    long i = t * 4;
    int row = (int)(i / K);
    int k   = (int)(i % K);
    float4 v = *reinterpret_cast<const float4*>(X + i);
    short4 hi, lo;
    split2(v.x, hi.x, lo.x); split2(v.y, hi.y, lo.y);
    split2(v.z, hi.z, lo.z); split2(v.w, hi.w, lo.w);
    short* base = A2 + (size_t)row * 2 * K + ((k >> 5) << 6) + (k & 31);
    *reinterpret_cast<short4*>(base)      = hi;
    *reinterpret_cast<short4*>(base + 32) = lo;
}

__global__ void k_split_bt(const float* __restrict__ Wa, const float* __restrict__ Wb,
                           int Na, int Nb, int K, short* __restrict__ Bt)
{
    int idx = blockIdx.x * blockDim.x + threadIdx.x;
    int N = Na + Nb;
    if (idx >= N * K) return;
    int j = idx / K, k = idx % K;
    float v = (j < Na) ? Wa[(size_t)k * Na + j] : Wb[(size_t)k * Nb + (j - Na)];
    short hi, lo;
    split2(v, hi, lo);
    short* base = Bt + (size_t)j * 2 * K + ((k >> 5) << 6) + (k & 31);
    base[0]  = hi;
    base[32] = lo;
}

// ---------------------------------------------------------------------------
// Split-bf16 MFMA GEMM, global_load_lds staging.
// LDS: linear 128B rows (A 128 rows, B BN rows). XOR swizzle s^(row&7) applied
// on the per-lane GLOBAL source (m173: gload_lds dest must be linear) and on
// the ds_read offsets -> <=2-way bank conflicts on fragment reads.
// 3 MFMA per k-chunk: hi*hi + hi*lo + lo*hi (lo*lo dropped, ~2^-18 rel).
// ---------------------------------------------------------------------------
template<int BN, bool BF16OUT>
__global__ __launch_bounds__(256) void k_mfma(
    const short* __restrict__ A2, const short* __restrict__ Bt,
    const float* __restrict__ bias, void* __restrict__ Cout,
    int M, int N, int K)
{
    constexpr int NI  = BN / 32;           // 16-col frags per wave
    constexpr int NBI = BN / 8;            // B gload instructions (8 rows each)
    __shared__ __align__(16) char lds[(128 + BN) * 128];

    const int tid  = threadIdx.x;
    const int lane = tid & 63;
    const int wid  = tid >> 6;
    const int wr   = wid >> 1;
    const int wc   = wid & 1;
    const int bm   = blockIdx.y * 128;
    const int bn   = blockIdx.x * BN;
    const size_t rowb = (size_t)4 * K;     // bytes per global row (2K shorts)

    f32x4 acc[4][NI] = {};
    const int lrow = lane & 15;
    const int c0   = lane >> 4;            // data chunk 0..3 (hi)
    const char* A2b = (const char*)A2;
    const char* Btb = (const char*)Bt;

    for (int kc = 0; kc < (K >> 5); ++kc) {
        // ---- stage A(16KB) + B(NBI KB) via global_load_lds width 16 ----
        for (int i = wid; i < 16 + NBI; i += 4) {
            bool isA = i < 16;
            int  i0  = isA ? i : i - 16;
            int  row = i0 * 8 + (lane >> 3);
            int  s   = lane & 7;
            int  sd  = s ^ (row & 7);          // pre-swizzled source chunk
            int  gr  = (isA ? bm : bn) + row;
            int  gmax = (isA ? M : N) - 1;
            if (gr > gmax) gr = gmax;          // clamp: OOB rows read valid data, discarded at store
            const char* src = (isA ? A2b : Btb) + (size_t)gr * rowb + kc * 128 + sd * 16;
            int dstoff = (isA ? 0 : 16384) + i0 * 1024;   // wave-uniform, linear
            __builtin_amdgcn_global_load_lds((const void*)src, (void*)&lds[dstoff], 16, 0, 0);
        }
        __syncthreads();

        // ---- fragments (swizzled ds_read_b128) ----
        short8 ah[4], al[4], bh[NI], bl[NI];
        #pragma unroll
        for (int mi = 0; mi < 4; ++mi) {
            int rl = wr * 64 + mi * 16 + lrow;
            int ch = c0 ^ (rl & 7);
            int cl = (c0 + 4) ^ (rl & 7);
            ah[mi] = *reinterpret_cast<const short8*>(&lds[rl * 128 + ch * 16]);
            al[mi] = *reinterpret_cast<const short8*>(&lds[rl * 128 + cl * 16]);
        }
        #pragma unroll
        for (int ni = 0; ni < NI; ++ni) {
            int rl = wc * (BN / 2) + ni * 16 + lrow;
            int ch = c0 ^ (rl & 7);
            int cl = (c0 + 4) ^ (rl & 7);
            bh[ni] = *reinterpret_cast<const short8*>(&lds[16384 + rl * 128 + ch * 16]);
            bl[ni] = *reinterpret_cast<const short8*>(&lds[16384 + rl * 128 + cl * 16]);
        }

        #pragma unroll
        for (int mi = 0; mi < 4; ++mi)
            #pragma unroll
            for (int ni = 0; ni < NI; ++ni) {
                acc[mi][ni] = __builtin_amdgcn_mfma_f32_16x16x32_bf16(ah[mi], bh[ni], acc[mi][ni], 0, 0, 0);
                acc[mi][ni] = __builtin_amdgcn_mfma_f32_16x16x32_bf16(ah[mi], bl[ni], acc[mi][ni], 0, 0, 0);
                acc[mi][ni] = __builtin_amdgcn_mfma_f32_16x16x32_bf16(al[mi], bh[ni], acc[mi][ni], 0, 0, 0);
            }
        __syncthreads();
    }

    // ---- epilogue: D row=(lane>>4)*4+q, col=lane&15 (m89-verified) ----
    #pragma unroll
    for (int mi = 0; mi < 4; ++mi)
        #pragma unroll
        for (int ni = 0; ni < NI; ++ni) {
            int row0 = bm + wr * 64 + mi * 16 + (lane >> 4) * 4;
            int col  = bn + wc * (BN / 2) + ni * 16 + (lane & 15);
            if (col >= N) continue;
            float badd = bias ? bias[col] : 0.f;
            #pragma unroll
            for (int q = 0; q < 4; ++q) {
                int row = row0 + q;
                if (row >= M) continue;
                float v = acc[mi][ni][q] + badd;
                if (BF16OUT)
                    ((unsigned short*)Cout)[(size_t)row * N + col] = bf16rne(v);
                else
                    ((float*)Cout)[(size_t)row * N + col] = v;
            }
        }
}

// ---------------------------------------------------------------------------
// Fused edge-logits + ONLINE segment-softmax + aggregation, single pass.
// Wave per node; per edge: gather bf16 row (8B/lane), logit via shfl reduce,
// online rescale of (m, s, acc) — no second gather pass.
// Writes split-bf16 interleaved rows for the next GEMM.
// ---------------------------------------------------------------------------
template<int VEC>   // channels C = VEC*64
__global__ __launch_bounds__(256) void k_fused(
    const unsigned short* __restrict__ xlr, int ldx, int xroff,
    const int* __restrict__ csr_src, const int* __restrict__ indptr,
    const float* __restrict__ att, const float* __restrict__ bias,
    short* __restrict__ outs, int n)
{
    const int C = VEC * 64;
    const int lane = threadIdx.x & 63;
    const int node = blockIdx.x * 4 + (threadIdx.x >> 6);
    if (node >= n) return;
    const int beg = indptr[node], end = indptr[node + 1];

    float attr[VEC], xri[VEC];
    if constexpr (VEC == 4) {
        float4 a = *reinterpret_cast<const float4*>(att + lane * 4);
        attr[0] = a.x; attr[1] = a.y; attr[2] = a.z; attr[3] = a.w;
        ushort4 r = *reinterpret_cast<const ushort4*>(xlr + (size_t)node * ldx + xroff + lane * 4);
        xri[0] = bf2f(r.x); xri[1] = bf2f(r.y); xri[2] = bf2f(r.z); xri[3] = bf2f(r.w);
    } else {
        float2 a = *reinterpret_cast<const float2*>(att + lane * 2);
        attr[0] = a.x; attr[1] = a.y;
        ushort2 r = *reinterpret_cast<const ushort2*>(xlr + (size_t)node * ldx + xroff + lane * 2);
        xri[0] = bf2f(r.x); xri[1] = bf2f(r.y);
    }

    float m = -3.4e38f, s = 0.f;
    float acc[VEC] = {};

    for (int base = beg; base < end; base += 64) {
        const int len = (end - base < 64) ? (end - base) : 64;
        int csr = (base + lane < end) ? csr_src[base + lane] : 0;

        // software-pipelined gather: prefetch row j+1 while reducing row j
        uint2 vb_n = make_uint2(0u, 0u);
        unsigned vb1_n = 0u;
        {
            int s0 = __shfl(csr, 0);
            if constexpr (VEC == 4)
                vb_n = *reinterpret_cast<const uint2*>(xlr + (size_t)s0 * ldx + lane * 4);
            else
                vb1_n = *reinterpret_cast<const unsigned*>(xlr + (size_t)s0 * ldx + lane * 2);
        }

        for (int j = 0; j < len; ++j) {
            float v[VEC];
            if constexpr (VEC == 4) {
                uint2 vb = vb_n;
                if (j + 1 < len) {
                    int s2 = __shfl(csr, j + 1);
                    vb_n = *reinterpret_cast<const uint2*>(xlr + (size_t)s2 * ldx + lane * 4);
                }
                v[0] = bf2f((unsigned short)(vb.x & 0xffffu));
                v[1] = bf2f((unsigned short)(vb.x >> 16));
                v[2] = bf2f((unsigned short)(vb.y & 0xffffu));
                v[3] = bf2f((unsigned short)(vb.y >> 16));
            } else {
                unsigned vb = vb1_n;
                if (j + 1 < len) {
                    int s2 = __shfl(csr, j + 1);
                    vb1_n = *reinterpret_cast<const unsigned*>(xlr + (size_t)s2 * ldx + lane * 2);
                }
                v[0] = bf2f((unsigned short)(vb & 0xffffu));
                v[1] = bf2f((unsigned short)(vb >> 16));
            }

            float p = 0.f;
            #pragma unroll
            for (int i = 0; i < VEC; ++i) {
                float t = v[i] + xri[i];
                t = t > 0.f ? t : NEG_SLOPE * t;
                p += attr[i] * t;
            }
            #pragma unroll
            for (int off = 1; off < 64; off <<= 1) p += __shfl_xor(p, off);

            // online softmax update (row j already in registers)
            float newm = fmaxf(m, p);
            float sc = __expf(m - newm);    // first edge: exp(-inf)=0
            float w  = __expf(p - newm);
            m = newm;
            s = s * sc + w;
            #pragma unroll
            for (int i = 0; i < VEC; ++i) acc[i] = acc[i] * sc + w * v[i];
        }
    }

    float inv = 1.f / s;
    int cbase = lane * VEC;
    short hi[VEC], lo[VEC];
    #pragma unroll
    for (int i = 0; i < VEC; ++i) {
        float o = fmaxf(acc[i] * inv + bias[cbase + i], 0.f);  // relu
        split2(o, hi[i], lo[i]);
    }
    short* obase = outs + (size_t)node * 2 * C + ((cbase >> 5) << 6) + (cbase & 31);
    if constexpr (VEC == 4) {
        *reinterpret_cast<short4*>(obase)      = make_short4(hi[0], hi[1], hi[2], hi[3]);
        *reinterpret_cast<short4*>(obase + 32) = make_short4(lo[0], lo[1], lo[2], lo[3]);
    } else {
        *reinterpret_cast<short2*>(obase)      = make_short2(hi[0], hi[1]);
        *reinterpret_cast<short2*>(obase + 32) = make_short2(lo[0], lo[1]);
    }
}

// ---------------------------------------------------------------------------
extern "C" void kernel_launch(void* const* d_in, const int* in_sizes, int n_in,
                              void* d_out, int out_size, void* d_ws, size_t ws_size,
                              hipStream_t stream)
{
    const float* x    = (const float*)d_in[0];
    const int*   ei   = (const int*)d_in[1];
    const float* W1l  = (const float*)d_in[2];
    const float* W1r  = (const float*)d_in[3];
    const float* att1 = (const float*)d_in[4];
    const float* b1   = (const float*)d_in[5];
    const float* W2l  = (const float*)d_in[6];
    const float* W2r  = (const float*)d_in[7];
    const float* att2 = (const float*)d_in[8];
    const float* b2   = (const float*)d_in[9];
    const float* Wc   = (const float*)d_in[10];
    const float* bc   = (const float*)d_in[11];

    const int h1 = in_sizes[4];        // 256
    const int h2 = in_sizes[8];        // 128
    const int c  = in_sizes[11];       // 40
    const int f  = in_sizes[2] / h1;   // 128
    const int n  = in_sizes[0] / f;    // 50000
    const int E  = in_sizes[1] / 2;    // 800000
    const int Etot = E + n;

    char* p = (char*)d_ws;
    auto alloc = [&](size_t bytes) -> char* {
        char* r = p; p += (bytes + 255) & ~(size_t)255; return r;
    };
    // 51.2 MB: xlr1 bf16 [n][2*h1]; later reused as xlr2 bf16 [n][2*h2]
    unsigned short* xlr1 = (unsigned short*)alloc((size_t)n * 2 * h1 * 2);
    // 51.2 MB: hsplit1 [n][2*h1] interleaved split-bf16
    short* hsplit1 = (short*)alloc((size_t)n * 2 * h1 * 2);
    // 25.6 MB: a2x [n][2*f]; later reused as hsplit2 [n][2*h2]
    short* a2x     = (short*)alloc((size_t)n * 2 * f * 2);
    short* bt1     = (short*)alloc((size_t)(2 * h1) * (2 * f) * 2);
    short* bt2     = (short*)alloc((size_t)(2 * h2) * (2 * h1) * 2);
    short* btc     = (short*)alloc((size_t)c * (2 * h2) * 2);
    int*   csr_src = (int*)alloc((size_t)Etot * 4);
    int*   indptr  = (int*)alloc((size_t)(n + 1) * 4);
    int*   cursor  = (int*)alloc((size_t)n * 4);
    int*   deg     = (int*)alloc((size_t)n * 4);
    int*   scanned = (int*)alloc((size_t)n * 4);
    int*   sums    = (int*)alloc(4096);

    unsigned short* xlr2 = xlr1;   // alias (xlr1 dead after fused1)
    short* hsplit2 = a2x;          // alias (a2x dead after L1 GEMM)

    const int tb = 256;

    // ---- conversions ----
    long total4 = (long)n * f / 4;
    k_split_a<<<(int)((total4 + tb - 1) / tb), tb, 0, stream>>>(x, a2x, total4, f);
    k_split_bt<<<(2 * h1 * f + tb - 1) / tb, tb, 0, stream>>>(W1l, W1r, h1, h1, f, bt1);
    k_split_bt<<<(2 * h2 * h1 + tb - 1) / tb, tb, 0, stream>>>(W2l, W2r, h2, h2, h1, bt2);
    k_split_bt<<<(c * h2 + tb - 1) / tb, tb, 0, stream>>>(Wc, nullptr, c, 0, h2, btc);

    // ---- CSR build ----
    hipMemsetAsync(deg, 0, (size_t)n * 4, stream);
    k_degree<<<(Etot + tb - 1) / tb, tb, 0, stream>>>(ei, E, n, deg);
    int nb = (n + SCAN_BLK - 1) / SCAN_BLK;
    k_scan1<<<nb, SCAN_BLK, 0, stream>>>(deg, scanned, sums, n);
    k_scan2<<<1, 64, 0, stream>>>(sums, nb);
    k_scan3<<<(n + tb - 1) / tb, tb, 0, stream>>>(scanned, sums, deg, indptr, cursor, n);
    k_scatter<<<(Etot + tb - 1) / tb, tb, 0, stream>>>(ei, E, n, cursor, csr_src);

    const int gy = (n + 127) / 128;

    // ---- Layer 1: xlr1(bf16) = x @ [W1l|W1r] ----
    k_mfma<128, true><<<dim3((2 * h1 + 127) / 128, gy), 256, 0, stream>>>(
        a2x, bt1, nullptr, xlr1, n, 2 * h1, f);
    k_fused<4><<<(n + 3) / 4, 256, 0, stream>>>(
        xlr1, 2 * h1, h1, csr_src, indptr, att1, b1, hsplit1, n);

    // ---- Layer 2: xlr2(bf16) = h1act @ [W2l|W2r] ----
    k_mfma<128, true><<<dim3((2 * h2 + 127) / 128, gy), 256, 0, stream>>>(
        hsplit1, bt2, nullptr, xlr2, n, 2 * h2, h1);
    k_fused<2><<<(n + 3) / 4, 256, 0, stream>>>(
        xlr2, 2 * h2, h2, csr_src, indptr, att2, b2, hsplit2, n);

    // ---- Classifier: d_out(fp32) = h2act @ Wc + bc ----
    k_mfma<64, false><<<dim3((c + 63) / 64, gy), 256, 0, stream>>>(
        hsplit2, btc, bc, d_out, n, c, h2);
}

// Round 13
// 447.936 us; speedup vs baseline: 2.5748x; 1.0724x over previous
//
#include <hip/hip_runtime.h>
#include <math.h>

#define NEG_SLOPE 0.2f

typedef __attribute__((ext_vector_type(8))) short short8;   // 8 bf16
typedef __attribute__((ext_vector_type(4))) float f32x4;

// Split fp32 into bf16 hi (truncate) + bf16 lo (RNE of exact remainder).
__device__ __forceinline__ void split2(float f, short& hi, short& lo)
{
    unsigned u  = __float_as_uint(f);
    unsigned hu = u & 0xffff0000u;
    hi = (short)(hu >> 16);
    float r = f - __uint_as_float(hu);           // exact
    unsigned ru = __float_as_uint(r);
    unsigned rnd = ru + 0x7fffu + ((ru >> 16) & 1u);
    lo = (short)(rnd >> 16);
}

__device__ __forceinline__ unsigned short bf16rne(float f)
{
    unsigned u = __float_as_uint(f);
    unsigned rnd = u + 0x7fffu + ((u >> 16) & 1u);
    return (unsigned short)(rnd >> 16);
}

__device__ __forceinline__ float bf2f_lo(unsigned u) { return __uint_as_float(u << 16); }
__device__ __forceinline__ float bf2f_hi(unsigned u) { return __uint_as_float(u & 0xffff0000u); }

// ---------------------------------------------------------------------------
// CSR build (unchanged)
// ---------------------------------------------------------------------------
__global__ void k_degree(const int* __restrict__ ei, int E, int n, int* __restrict__ deg)
{
    int e = blockIdx.x * blockDim.x + threadIdx.x;
    int etot = E + n;
    if (e < etot) {
        int dst = (e < E) ? ei[E + e] : (e - E);
        atomicAdd(&deg[dst], 1);
    }
}

#define SCAN_BLK 1024
__global__ void k_scan1(const int* __restrict__ deg, int* __restrict__ scanned,
                        int* __restrict__ sums, int n)
{
    __shared__ int sh[SCAN_BLK];
    int base = blockIdx.x * SCAN_BLK;
    int t = threadIdx.x;
    int v = (base + t < n) ? deg[base + t] : 0;
    sh[t] = v;
    __syncthreads();
    for (int off = 1; off < SCAN_BLK; off <<= 1) {
        int x = (t >= off) ? sh[t - off] : 0;
        __syncthreads();
        sh[t] += x;
        __syncthreads();
    }
    if (base + t < n) scanned[base + t] = sh[t];
    if (t == SCAN_BLK - 1) sums[blockIdx.x] = sh[t];
}

__global__ void k_scan2(int* __restrict__ sums, int nb)
{
    if (threadIdx.x == 0 && blockIdx.x == 0) {
        int run = 0;
        for (int i = 0; i < nb; ++i) { int v = sums[i]; sums[i] = run; run += v; }
    }
}

__global__ void k_scan3(const int* __restrict__ scanned, const int* __restrict__ sums,
                        const int* __restrict__ deg, int* __restrict__ indptr,
                        int* __restrict__ cursor, int n)
{
    int i = blockIdx.x * blockDim.x + threadIdx.x;
    if (i < n) {
        int incl = scanned[i] + sums[i / SCAN_BLK];
        indptr[i + 1] = incl;
        cursor[i] = incl - deg[i];
        if (i == 0) indptr[0] = 0;
    }
}

__global__ void k_scatter(const int* __restrict__ ei, int E, int n,
                          int* __restrict__ cursor, int* __restrict__ csr_src)
{
    int e = blockIdx.x * blockDim.x + threadIdx.x;
    int etot = E + n;
    if (e < etot) {
        int src, dst;
        if (e < E) { src = ei[e]; dst = ei[E + e]; }
        else       { src = dst = e - E; }
        int pos = atomicAdd(&cursor[dst], 1);
        csr_src[pos] = src;
    }
}

// ---------------------------------------------------------------------------
// Conversions -> interleaved split layout: row = [hi32|lo32][hi32|lo32]...
// element k: idx = row*2K + ((k>>5)<<6) + (k&31); lo at idx+32.
// ---------------------------------------------------------------------------
__global__ void k_split_a(const float* __restrict__ X, short* __restrict__ A2,
                          long total4, int K)
{
    long t = (long)blockIdx.x * blockDim.x + threadIdx.x;
    if (t >= total4) return;
    long i = t * 4;
    int row = (int)(i / K);
    int k   = (int)(i % K);
    float4 v = *reinterpret_cast<const float4*>(X + i);
    short4 hi, lo;
    split2(v.x, hi.x, lo.x); split2(v.y, hi.y, lo.y);
    split2(v.z, hi.z, lo.z); split2(v.w, hi.w, lo.w);
    short* base = A2 + (size_t)row * 2 * K + ((k >> 5) << 6) + (k & 31);
    *reinterpret_cast<short4*>(base)      = hi;
    *reinterpret_cast<short4*>(base + 32) = lo;
}

__global__ void k_split_bt(const float* __restrict__ Wa, const float* __restrict__ Wb,
                           int Na, int Nb, int K, short* __restrict__ Bt)
{
    int idx = blockIdx.x * blockDim.x + threadIdx.x;
    int N = Na + Nb;
    if (idx >= N * K) return;
    int j = idx / K, k = idx % K;
    float v = (j < Na) ? Wa[(size_t)k * Na + j] : Wb[(size_t)k * Nb + (j - Na)];
    short hi, lo;
    split2(v, hi, lo);
    short* base = Bt + (size_t)j * 2 * K + ((k >> 5) << 6) + (k & 31);
    base[0]  = hi;
    base[32] = lo;
}

// ---------------------------------------------------------------------------
// Split-bf16 MFMA GEMM, global_load_lds staging (unchanged from round 12).
// ---------------------------------------------------------------------------
template<int BN, bool BF16OUT>
__global__ __launch_bounds__(256) void k_mfma(
    const short* __restrict__ A2, const short* __restrict__ Bt,
    const float* __restrict__ bias, void* __restrict__ Cout,
    int M, int N, int K)
{
    constexpr int NI  = BN / 32;
    constexpr int NBI = BN / 8;
    __shared__ __align__(16) char lds[(128 + BN) * 128];

    const int tid  = threadIdx.x;
    const int lane = tid & 63;
    const int wid  = tid >> 6;
    const int wr   = wid >> 1;
    const int wc   = wid & 1;
    const int bm   = blockIdx.y * 128;
    const int bn   = blockIdx.x * BN;
    const size_t rowb = (size_t)4 * K;

    f32x4 acc[4][NI] = {};
    const int lrow = lane & 15;
    const int c0   = lane >> 4;
    const char* A2b = (const char*)A2;
    const char* Btb = (const char*)Bt;

    for (int kc = 0; kc < (K >> 5); ++kc) {
        for (int i = wid; i < 16 + NBI; i += 4) {
            bool isA = i < 16;
            int  i0  = isA ? i : i - 16;
            int  row = i0 * 8 + (lane >> 3);
            int  s   = lane & 7;
            int  sd  = s ^ (row & 7);
            int  gr  = (isA ? bm : bn) + row;
            int  gmax = (isA ? M : N) - 1;
            if (gr > gmax) gr = gmax;
            const char* src = (isA ? A2b : Btb) + (size_t)gr * rowb + kc * 128 + sd * 16;
            int dstoff = (isA ? 0 : 16384) + i0 * 1024;
            __builtin_amdgcn_global_load_lds((const void*)src, (void*)&lds[dstoff], 16, 0, 0);
        }
        __syncthreads();

        short8 ah[4], al[4], bh[NI], bl[NI];
        #pragma unroll
        for (int mi = 0; mi < 4; ++mi) {
            int rl = wr * 64 + mi * 16 + lrow;
            int ch = c0 ^ (rl & 7);
            int cl = (c0 + 4) ^ (rl & 7);
            ah[mi] = *reinterpret_cast<const short8*>(&lds[rl * 128 + ch * 16]);
            al[mi] = *reinterpret_cast<const short8*>(&lds[rl * 128 + cl * 16]);
        }
        #pragma unroll
        for (int ni = 0; ni < NI; ++ni) {
            int rl = wc * (BN / 2) + ni * 16 + lrow;
            int ch = c0 ^ (rl & 7);
            int cl = (c0 + 4) ^ (rl & 7);
            bh[ni] = *reinterpret_cast<const short8*>(&lds[16384 + rl * 128 + ch * 16]);
            bl[ni] = *reinterpret_cast<const short8*>(&lds[16384 + rl * 128 + cl * 16]);
        }

        #pragma unroll
        for (int mi = 0; mi < 4; ++mi)
            #pragma unroll
            for (int ni = 0; ni < NI; ++ni) {
                acc[mi][ni] = __builtin_amdgcn_mfma_f32_16x16x32_bf16(ah[mi], bh[ni], acc[mi][ni], 0, 0, 0);
                acc[mi][ni] = __builtin_amdgcn_mfma_f32_16x16x32_bf16(ah[mi], bl[ni], acc[mi][ni], 0, 0, 0);
                acc[mi][ni] = __builtin_amdgcn_mfma_f32_16x16x32_bf16(al[mi], bh[ni], acc[mi][ni], 0, 0, 0);
            }
        __syncthreads();
    }

    #pragma unroll
    for (int mi = 0; mi < 4; ++mi)
        #pragma unroll
        for (int ni = 0; ni < NI; ++ni) {
            int row0 = bm + wr * 64 + mi * 16 + (lane >> 4) * 4;
            int col  = bn + wc * (BN / 2) + ni * 16 + (lane & 15);
            if (col >= N) continue;
            float badd = bias ? bias[col] : 0.f;
            #pragma unroll
            for (int q = 0; q < 4; ++q) {
                int row = row0 + q;
                if (row >= M) continue;
                float v = acc[mi][ni][q] + badd;
                if (BF16OUT)
                    ((unsigned short*)Cout)[(size_t)row * N + col] = bf16rne(v);
                else
                    ((float*)Cout)[(size_t)row * N + col] = v;
            }
        }
}

// ---------------------------------------------------------------------------
// Fused edge-logits + online segment-softmax + aggregation.
// NSUB nodes per wave, LSUB=64/NSUB lanes per node, 8 channels per lane
// (C = 8*LSUB). Shorter reduce (log2(LSUB) steps) and the online-softmax /
// loop-overhead instructions are shared by NSUB nodes per issue.
// ---------------------------------------------------------------------------
template<int NSUB>   // NSUB=2 -> C=256, NSUB=4 -> C=128
__global__ __launch_bounds__(256) void k_fused(
    const unsigned short* __restrict__ xlr, int ldx, int xroff,
    const int* __restrict__ csr_src, const int* __restrict__ indptr,
    const float* __restrict__ att, const float* __restrict__ bias,
    short* __restrict__ outs, int n)
{
    constexpr int LSUB = 64 / NSUB;        // lanes per node
    constexpr int C = 8 * LSUB;
    const int lane = threadIdx.x & 63;
    const int wid  = threadIdx.x >> 6;
    const int sub  = lane / LSUB;
    const int sl   = lane % LSUB;
    const int node = blockIdx.x * (4 * NSUB) + wid * NSUB + sub;
    const bool valid = node < n;
    const int nodec = valid ? node : 0;
    const int beg = indptr[nodec];
    const int end = valid ? indptr[nodec + 1] : beg;

    // 8 channels per lane
    float attr[8], xri[8];
    {
        float4 a0 = *reinterpret_cast<const float4*>(att + sl * 8);
        float4 a1 = *reinterpret_cast<const float4*>(att + sl * 8 + 4);
        attr[0]=a0.x; attr[1]=a0.y; attr[2]=a0.z; attr[3]=a0.w;
        attr[4]=a1.x; attr[5]=a1.y; attr[6]=a1.z; attr[7]=a1.w;
        uint4 r = *reinterpret_cast<const uint4*>(xlr + (size_t)nodec * ldx + xroff + sl * 8);
        xri[0]=bf2f_lo(r.x); xri[1]=bf2f_hi(r.x);
        xri[2]=bf2f_lo(r.y); xri[3]=bf2f_hi(r.y);
        xri[4]=bf2f_lo(r.z); xri[5]=bf2f_hi(r.z);
        xri[6]=bf2f_lo(r.w); xri[7]=bf2f_hi(r.w);
    }

    float m = -3.4e38f, s = 0.f;
    float acc[8] = {};

    // wave-uniform chunk count: max degree among this wave's subs
    int deg = end - beg;
    int mdeg = deg;
    if constexpr (NSUB == 4) mdeg = max(mdeg, __shfl_xor(mdeg, 16));
    mdeg = max(mdeg, __shfl_xor(mdeg, 32));
    const int nch = (mdeg + LSUB - 1) / LSUB;

    for (int it = 0; it < nch; ++it) {
        const int base = beg + it * LSUB;
        int len = end - base;
        len = len < 0 ? 0 : (len > LSUB ? LSUB : len);
        const int csr = (sl < len) ? csr_src[base + sl] : 0;
        // wave-uniform inner bound: max len among subs
        int wlen = len;
        if constexpr (NSUB == 4) wlen = max(wlen, __shfl_xor(wlen, 16));
        wlen = max(wlen, __shfl_xor(wlen, 32));

        for (int j = 0; j < wlen; ++j) {
            const bool active = j < len;            // sub-uniform
            const int src = __shfl(csr, sub * LSUB + j);
            float v[8];
            float p = 0.f;
            if (active) {
                uint4 vb = *reinterpret_cast<const uint4*>(xlr + (size_t)src * ldx + sl * 8);
                v[0]=bf2f_lo(vb.x); v[1]=bf2f_hi(vb.x);
                v[2]=bf2f_lo(vb.y); v[3]=bf2f_hi(vb.y);
                v[4]=bf2f_lo(vb.z); v[5]=bf2f_hi(vb.z);
                v[6]=bf2f_lo(vb.w); v[7]=bf2f_hi(vb.w);
                #pragma unroll
                for (int i = 0; i < 8; ++i) {
                    float t = v[i] + xri[i];
                    t = fmaxf(t, NEG_SLOPE * t);    // leaky-relu
                    p += attr[i] * t;
                }
            }
            #pragma unroll
            for (int off = 1; off < LSUB; off <<= 1) p += __shfl_xor(p, off);

            if (active) {
                float newm = fmaxf(m, p);
                float sc = __expf(m - newm);        // first edge: exp(-inf)=0
                float w  = __expf(p - newm);
                m = newm;
                s = s * sc + w;
                #pragma unroll
                for (int i = 0; i < 8; ++i) acc[i] = acc[i] * sc + w * v[i];
            }
        }
    }

    if (valid) {
        float inv = 1.f / s;
        int cbase = sl * 8;
        short hi[8], lo[8];
        #pragma unroll
        for (int i = 0; i < 8; ++i) {
            float o = fmaxf(acc[i] * inv + bias[cbase + i], 0.f);  // relu
            split2(o, hi[i], lo[i]);
        }
        short* obase = outs + (size_t)node * 2 * C + ((cbase >> 5) << 6) + (cbase & 31);
        *reinterpret_cast<short4*>(obase)          = make_short4(hi[0], hi[1], hi[2], hi[3]);
        *reinterpret_cast<short4*>(obase + 4)      = make_short4(hi[4], hi[5], hi[6], hi[7]);
        *reinterpret_cast<short4*>(obase + 32)     = make_short4(lo[0], lo[1], lo[2], lo[3]);
        *reinterpret_cast<short4*>(obase + 36)     = make_short4(lo[4], lo[5], lo[6], lo[7]);
    }
}

// ---------------------------------------------------------------------------
extern "C" void kernel_launch(void* const* d_in, const int* in_sizes, int n_in,
                              void* d_out, int out_size, void* d_ws, size_t ws_size,
                              hipStream_t stream)
{
    const float* x    = (const float*)d_in[0];
    const int*   ei   = (const int*)d_in[1];
    const float* W1l  = (const float*)d_in[2];
    const float* W1r  = (const float*)d_in[3];
    const float* att1 = (const float*)d_in[4];
    const float* b1   = (const float*)d_in[5];
    const float* W2l  = (const float*)d_in[6];
    const float* W2r  = (const float*)d_in[7];
    const float* att2 = (const float*)d_in[8];
    const float* b2   = (const float*)d_in[9];
    const float* Wc   = (const float*)d_in[10];
    const float* bc   = (const float*)d_in[11];

    const int h1 = in_sizes[4];        // 256
    const int h2 = in_sizes[8];        // 128
    const int c  = in_sizes[11];       // 40
    const int f  = in_sizes[2] / h1;   // 128
    const int n  = in_sizes[0] / f;    // 50000
    const int E  = in_sizes[1] / 2;    // 800000
    const int Etot = E + n;

    char* p = (char*)d_ws;
    auto alloc = [&](size_t bytes) -> char* {
        char* r = p; p += (bytes + 255) & ~(size_t)255; return r;
    };
    unsigned short* xlr1 = (unsigned short*)alloc((size_t)n * 2 * h1 * 2);
    short* hsplit1 = (short*)alloc((size_t)n * 2 * h1 * 2);
    short* a2x     = (short*)alloc((size_t)n * 2 * f * 2);
    short* bt1     = (short*)alloc((size_t)(2 * h1) * (2 * f) * 2);
    short* bt2     = (short*)alloc((size_t)(2 * h2) * (2 * h1) * 2);
    short* btc     = (short*)alloc((size_t)c * (2 * h2) * 2);
    int*   csr_src = (int*)alloc((size_t)Etot * 4);
    int*   indptr  = (int*)alloc((size_t)(n + 1) * 4);
    int*   cursor  = (int*)alloc((size_t)n * 4);
    int*   deg     = (int*)alloc((size_t)n * 4);
    int*   scanned = (int*)alloc((size_t)n * 4);
    int*   sums    = (int*)alloc(4096);

    unsigned short* xlr2 = xlr1;   // alias (xlr1 dead after fused1)
    short* hsplit2 = a2x;          // alias (a2x dead after L1 GEMM)

    const int tb = 256;

    // ---- conversions ----
    long total4 = (long)n * f / 4;
    k_split_a<<<(int)((total4 + tb - 1) / tb), tb, 0, stream>>>(x, a2x, total4, f);
    k_split_bt<<<(2 * h1 * f + tb - 1) / tb, tb, 0, stream>>>(W1l, W1r, h1, h1, f, bt1);
    k_split_bt<<<(2 * h2 * h1 + tb - 1) / tb, tb, 0, stream>>>(W2l, W2r, h2, h2, h1, bt2);
    k_split_bt<<<(c * h2 + tb - 1) / tb, tb, 0, stream>>>(Wc, nullptr, c, 0, h2, btc);

    // ---- CSR build ----
    hipMemsetAsync(deg, 0, (size_t)n * 4, stream);
    k_degree<<<(Etot + tb - 1) / tb, tb, 0, stream>>>(ei, E, n, deg);
    int nb = (n + SCAN_BLK - 1) / SCAN_BLK;
    k_scan1<<<nb, SCAN_BLK, 0, stream>>>(deg, scanned, sums, n);
    k_scan2<<<1, 64, 0, stream>>>(sums, nb);
    k_scan3<<<(n + tb - 1) / tb, tb, 0, stream>>>(scanned, sums, deg, indptr, cursor, n);
    k_scatter<<<(Etot + tb - 1) / tb, tb, 0, stream>>>(ei, E, n, cursor, csr_src);

    const int gy = (n + 127) / 128;

    // ---- Layer 1: xlr1(bf16) = x @ [W1l|W1r]; fused: 2 nodes/wave (C=256) ----
    k_mfma<128, true><<<dim3((2 * h1 + 127) / 128, gy), 256, 0, stream>>>(
        a2x, bt1, nullptr, xlr1, n, 2 * h1, f);
    k_fused<2><<<(n + 7) / 8, 256, 0, stream>>>(
        xlr1, 2 * h1, h1, csr_src, indptr, att1, b1, hsplit1, n);

    // ---- Layer 2: fused: 4 nodes/wave (C=128) ----
    k_mfma<128, true><<<dim3((2 * h2 + 127) / 128, gy), 256, 0, stream>>>(
        hsplit1, bt2, nullptr, xlr2, n, 2 * h2, h1);
    k_fused<4><<<(n + 15) / 16, 256, 0, stream>>>(
        xlr2, 2 * h2, h2, csr_src, indptr, att2, b2, hsplit2, n);

    // ---- Classifier: d_out(fp32) = h2act @ Wc + bc ----
    k_mfma<64, false><<<dim3((c + 63) / 64, gy), 256, 0, stream>>>(
        hsplit2, btc, bc, d_out, n, c, h2);
}

// Round 14
// 426.358 us; speedup vs baseline: 2.7052x; 1.0506x over previous
//
#include <hip/hip_runtime.h>
#include <math.h>

#define NEG_SLOPE 0.2f

typedef __attribute__((ext_vector_type(8))) short short8;   // 8 bf16
typedef __attribute__((ext_vector_type(4))) float f32x4;

// Split fp32 into bf16 hi (truncate) + bf16 lo (RNE of exact remainder).
__device__ __forceinline__ void split2(float f, short& hi, short& lo)
{
    unsigned u  = __float_as_uint(f);
    unsigned hu = u & 0xffff0000u;
    hi = (short)(hu >> 16);
    float r = f - __uint_as_float(hu);           // exact
    unsigned ru = __float_as_uint(r);
    unsigned rnd = ru + 0x7fffu + ((ru >> 16) & 1u);
    lo = (short)(rnd >> 16);
}

__device__ __forceinline__ unsigned short bf16rne(float f)
{
    unsigned u = __float_as_uint(f);
    unsigned rnd = u + 0x7fffu + ((u >> 16) & 1u);
    return (unsigned short)(rnd >> 16);
}

__device__ __forceinline__ float bf2f_lo(unsigned u) { return __uint_as_float(u << 16); }
__device__ __forceinline__ float bf2f_hi(unsigned u) { return __uint_as_float(u & 0xffff0000u); }

// ---------------------------------------------------------------------------
// CSR build (unchanged)
// ---------------------------------------------------------------------------
__global__ void k_degree(const int* __restrict__ ei, int E, int n, int* __restrict__ deg)
{
    int e = blockIdx.x * blockDim.x + threadIdx.x;
    int etot = E + n;
    if (e < etot) {
        int dst = (e < E) ? ei[E + e] : (e - E);
        atomicAdd(&deg[dst], 1);
    }
}

#define SCAN_BLK 1024
__global__ void k_scan1(const int* __restrict__ deg, int* __restrict__ scanned,
                        int* __restrict__ sums, int n)
{
    __shared__ int sh[SCAN_BLK];
    int base = blockIdx.x * SCAN_BLK;
    int t = threadIdx.x;
    int v = (base + t < n) ? deg[base + t] : 0;
    sh[t] = v;
    __syncthreads();
    for (int off = 1; off < SCAN_BLK; off <<= 1) {
        int x = (t >= off) ? sh[t - off] : 0;
        __syncthreads();
        sh[t] += x;
        __syncthreads();
    }
    if (base + t < n) scanned[base + t] = sh[t];
    if (t == SCAN_BLK - 1) sums[blockIdx.x] = sh[t];
}

__global__ void k_scan2(int* __restrict__ sums, int nb)
{
    if (threadIdx.x == 0 && blockIdx.x == 0) {
        int run = 0;
        for (int i = 0; i < nb; ++i) { int v = sums[i]; sums[i] = run; run += v; }
    }
}

__global__ void k_scan3(const int* __restrict__ scanned, const int* __restrict__ sums,
                        const int* __restrict__ deg, int* __restrict__ indptr,
                        int* __restrict__ cursor, int n)
{
    int i = blockIdx.x * blockDim.x + threadIdx.x;
    if (i < n) {
        int incl = scanned[i] + sums[i / SCAN_BLK];
        indptr[i + 1] = incl;
        cursor[i] = incl - deg[i];
        if (i == 0) indptr[0] = 0;
    }
}

__global__ void k_scatter(const int* __restrict__ ei, int E, int n,
                          int* __restrict__ cursor, int* __restrict__ csr_src)
{
    int e = blockIdx.x * blockDim.x + threadIdx.x;
    int etot = E + n;
    if (e < etot) {
        int src, dst;
        if (e < E) { src = ei[e]; dst = ei[E + e]; }
        else       { src = dst = e - E; }
        int pos = atomicAdd(&cursor[dst], 1);
        csr_src[pos] = src;
    }
}

// ---------------------------------------------------------------------------
// Conversions -> interleaved split layout: row = [hi32|lo32][hi32|lo32]...
// ---------------------------------------------------------------------------
__global__ void k_split_a(const float* __restrict__ X, short* __restrict__ A2,
                          long total4, int K)
{
    long t = (long)blockIdx.x * blockDim.x + threadIdx.x;
    if (t >= total4) return;
    long i = t * 4;
    int row = (int)(i / K);
    int k   = (int)(i % K);
    float4 v = *reinterpret_cast<const float4*>(X + i);
    short4 hi, lo;
    split2(v.x, hi.x, lo.x); split2(v.y, hi.y, lo.y);
    split2(v.z, hi.z, lo.z); split2(v.w, hi.w, lo.w);
    short* base = A2 + (size_t)row * 2 * K + ((k >> 5) << 6) + (k & 31);
    *reinterpret_cast<short4*>(base)      = hi;
    *reinterpret_cast<short4*>(base + 32) = lo;
}

__global__ void k_split_bt(const float* __restrict__ Wa, const float* __restrict__ Wb,
                           int Na, int Nb, int K, short* __restrict__ Bt)
{
    int idx = blockIdx.x * blockDim.x + threadIdx.x;
    int N = Na + Nb;
    if (idx >= N * K) return;
    int j = idx / K, k = idx % K;
    float v = (j < Na) ? Wa[(size_t)k * Na + j] : Wb[(size_t)k * Nb + (j - Na)];
    short hi, lo;
    split2(v, hi, lo);
    short* base = Bt + (size_t)j * 2 * K + ((k >> 5) << 6) + (k & 31);
    base[0]  = hi;
    base[32] = lo;
}

// ---------------------------------------------------------------------------
// Split-bf16 MFMA GEMM, global_load_lds staging (unchanged from round 12).
// ---------------------------------------------------------------------------
template<int BN, bool BF16OUT>
__global__ __launch_bounds__(256) void k_mfma(
    const short* __restrict__ A2, const short* __restrict__ Bt,
    const float* __restrict__ bias, void* __restrict__ Cout,
    int M, int N, int K)
{
    constexpr int NI  = BN / 32;
    constexpr int NBI = BN / 8;
    __shared__ __align__(16) char lds[(128 + BN) * 128];

    const int tid  = threadIdx.x;
    const int lane = tid & 63;
    const int wid  = tid >> 6;
    const int wr   = wid >> 1;
    const int wc   = wid & 1;
    const int bm   = blockIdx.y * 128;
    const int bn   = blockIdx.x * BN;
    const size_t rowb = (size_t)4 * K;

    f32x4 acc[4][NI] = {};
    const int lrow = lane & 15;
    const int c0   = lane >> 4;
    const char* A2b = (const char*)A2;
    const char* Btb = (const char*)Bt;

    for (int kc = 0; kc < (K >> 5); ++kc) {
        for (int i = wid; i < 16 + NBI; i += 4) {
            bool isA = i < 16;
            int  i0  = isA ? i : i - 16;
            int  row = i0 * 8 + (lane >> 3);
            int  s   = lane & 7;
            int  sd  = s ^ (row & 7);
            int  gr  = (isA ? bm : bn) + row;
            int  gmax = (isA ? M : N) - 1;
            if (gr > gmax) gr = gmax;
            const char* src = (isA ? A2b : Btb) + (size_t)gr * rowb + kc * 128 + sd * 16;
            int dstoff = (isA ? 0 : 16384) + i0 * 1024;
            __builtin_amdgcn_global_load_lds((const void*)src, (void*)&lds[dstoff], 16, 0, 0);
        }
        __syncthreads();

        short8 ah[4], al[4], bh[NI], bl[NI];
        #pragma unroll
        for (int mi = 0; mi < 4; ++mi) {
            int rl = wr * 64 + mi * 16 + lrow;
            int ch = c0 ^ (rl & 7);
            int cl = (c0 + 4) ^ (rl & 7);
            ah[mi] = *reinterpret_cast<const short8*>(&lds[rl * 128 + ch * 16]);
            al[mi] = *reinterpret_cast<const short8*>(&lds[rl * 128 + cl * 16]);
        }
        #pragma unroll
        for (int ni = 0; ni < NI; ++ni) {
            int rl = wc * (BN / 2) + ni * 16 + lrow;
            int ch = c0 ^ (rl & 7);
            int cl = (c0 + 4) ^ (rl & 7);
            bh[ni] = *reinterpret_cast<const short8*>(&lds[16384 + rl * 128 + ch * 16]);
            bl[ni] = *reinterpret_cast<const short8*>(&lds[16384 + rl * 128 + cl * 16]);
        }

        #pragma unroll
        for (int mi = 0; mi < 4; ++mi)
            #pragma unroll
            for (int ni = 0; ni < NI; ++ni) {
                acc[mi][ni] = __builtin_amdgcn_mfma_f32_16x16x32_bf16(ah[mi], bh[ni], acc[mi][ni], 0, 0, 0);
                acc[mi][ni] = __builtin_amdgcn_mfma_f32_16x16x32_bf16(ah[mi], bl[ni], acc[mi][ni], 0, 0, 0);
                acc[mi][ni] = __builtin_amdgcn_mfma_f32_16x16x32_bf16(al[mi], bh[ni], acc[mi][ni], 0, 0, 0);
            }
        __syncthreads();
    }

    #pragma unroll
    for (int mi = 0; mi < 4; ++mi)
        #pragma unroll
        for (int ni = 0; ni < NI; ++ni) {
            int row0 = bm + wr * 64 + mi * 16 + (lane >> 4) * 4;
            int col  = bn + wc * (BN / 2) + ni * 16 + (lane & 15);
            if (col >= N) continue;
            float badd = bias ? bias[col] : 0.f;
            #pragma unroll
            for (int q = 0; q < 4; ++q) {
                int row = row0 + q;
                if (row >= M) continue;
                float v = acc[mi][ni][q] + badd;
                if (BF16OUT)
                    ((unsigned short*)Cout)[(size_t)row * N + col] = bf16rne(v);
                else
                    ((float*)Cout)[(size_t)row * N + col] = v;
            }
        }
}

// ---------------------------------------------------------------------------
// Fused edge-logits + online segment-softmax + aggregation.
// NSUB nodes per wave, LSUB=64/NSUB lanes per node, 8 channels per lane.
// Round 14: software-pipelined gather restored (prefetch row j+1 during row j).
// ---------------------------------------------------------------------------
template<int NSUB>   // NSUB=2 -> C=256, NSUB=4 -> C=128
__global__ __launch_bounds__(256) void k_fused(
    const unsigned short* __restrict__ xlr, int ldx, int xroff,
    const int* __restrict__ csr_src, const int* __restrict__ indptr,
    const float* __restrict__ att, const float* __restrict__ bias,
    short* __restrict__ outs, int n)
{
    constexpr int LSUB = 64 / NSUB;        // lanes per node
    constexpr int C = 8 * LSUB;
    const int lane = threadIdx.x & 63;
    const int wid  = threadIdx.x >> 6;
    const int sub  = lane / LSUB;
    const int sl   = lane % LSUB;
    const int node = blockIdx.x * (4 * NSUB) + wid * NSUB + sub;
    const bool valid = node < n;
    const int nodec = valid ? node : 0;
    const int beg = indptr[nodec];
    const int end = valid ? indptr[nodec + 1] : beg;

    float attr[8], xri[8];
    {
        float4 a0 = *reinterpret_cast<const float4*>(att + sl * 8);
        float4 a1 = *reinterpret_cast<const float4*>(att + sl * 8 + 4);
        attr[0]=a0.x; attr[1]=a0.y; attr[2]=a0.z; attr[3]=a0.w;
        attr[4]=a1.x; attr[5]=a1.y; attr[6]=a1.z; attr[7]=a1.w;
        uint4 r = *reinterpret_cast<const uint4*>(xlr + (size_t)nodec * ldx + xroff + sl * 8);
        xri[0]=bf2f_lo(r.x); xri[1]=bf2f_hi(r.x);
        xri[2]=bf2f_lo(r.y); xri[3]=bf2f_hi(r.y);
        xri[4]=bf2f_lo(r.z); xri[5]=bf2f_hi(r.z);
        xri[6]=bf2f_lo(r.w); xri[7]=bf2f_hi(r.w);
    }

    float m = -3.4e38f, s = 0.f;
    float acc[8] = {};

    int deg = end - beg;
    int mdeg = deg;
    if constexpr (NSUB == 4) mdeg = max(mdeg, __shfl_xor(mdeg, 16));
    mdeg = max(mdeg, __shfl_xor(mdeg, 32));
    const int nch = (mdeg + LSUB - 1) / LSUB;

    for (int it = 0; it < nch; ++it) {
        const int base = beg + it * LSUB;
        int len = end - base;
        len = len < 0 ? 0 : (len > LSUB ? LSUB : len);
        const int csr = (sl < len) ? csr_src[base + sl] : 0;
        int wlen = len;
        if constexpr (NSUB == 4) wlen = max(wlen, __shfl_xor(wlen, 16));
        wlen = max(wlen, __shfl_xor(wlen, 32));

        // prologue: prefetch row j=0
        uint4 vb_n = make_uint4(0u, 0u, 0u, 0u);
        {
            int s0 = __shfl(csr, sub * LSUB);
            if (0 < len)
                vb_n = *reinterpret_cast<const uint4*>(xlr + (size_t)s0 * ldx + sl * 8);
        }

        for (int j = 0; j < wlen; ++j) {
            const bool active = j < len;            // sub-uniform
            uint4 vb = vb_n;
            // prefetch row j+1 (overlaps with this row's compute)
            {
                int nidx = sub * LSUB + j + 1;
                int s2 = __shfl(csr, nidx & 63);
                if (j + 1 < len)
                    vb_n = *reinterpret_cast<const uint4*>(xlr + (size_t)s2 * ldx + sl * 8);
            }

            float v[8];
            float p = 0.f;
            if (active) {
                v[0]=bf2f_lo(vb.x); v[1]=bf2f_hi(vb.x);
                v[2]=bf2f_lo(vb.y); v[3]=bf2f_hi(vb.y);
                v[4]=bf2f_lo(vb.z); v[5]=bf2f_hi(vb.z);
                v[6]=bf2f_lo(vb.w); v[7]=bf2f_hi(vb.w);
                #pragma unroll
                for (int i = 0; i < 8; ++i) {
                    float t = v[i] + xri[i];
                    t = fmaxf(t, NEG_SLOPE * t);    // leaky-relu
                    p += attr[i] * t;
                }
            }
            #pragma unroll
            for (int off = 1; off < LSUB; off <<= 1) p += __shfl_xor(p, off);

            if (active) {
                float newm = fmaxf(m, p);
                float sc = __expf(m - newm);        // first edge: exp(-inf)=0
                float w  = __expf(p - newm);
                m = newm;
                s = s * sc + w;
                #pragma unroll
                for (int i = 0; i < 8; ++i) acc[i] = acc[i] * sc + w * v[i];
            }
        }
    }

    if (valid) {
        float inv = 1.f / s;
        int cbase = sl * 8;
        short hi[8], lo[8];
        #pragma unroll
        for (int i = 0; i < 8; ++i) {
            float o = fmaxf(acc[i] * inv + bias[cbase + i], 0.f);  // relu
            split2(o, hi[i], lo[i]);
        }
        short* obase = outs + (size_t)node * 2 * C + ((cbase >> 5) << 6) + (cbase & 31);
        *reinterpret_cast<short4*>(obase)          = make_short4(hi[0], hi[1], hi[2], hi[3]);
        *reinterpret_cast<short4*>(obase + 4)      = make_short4(hi[4], hi[5], hi[6], hi[7]);
        *reinterpret_cast<short4*>(obase + 32)     = make_short4(lo[0], lo[1], lo[2], lo[3]);
        *reinterpret_cast<short4*>(obase + 36)     = make_short4(lo[4], lo[5], lo[6], lo[7]);
    }
}

// ---------------------------------------------------------------------------
extern "C" void kernel_launch(void* const* d_in, const int* in_sizes, int n_in,
                              void* d_out, int out_size, void* d_ws, size_t ws_size,
                              hipStream_t stream)
{
    const float* x    = (const float*)d_in[0];
    const int*   ei   = (const int*)d_in[1];
    const float* W1l  = (const float*)d_in[2];
    const float* W1r  = (const float*)d_in[3];
    const float* att1 = (const float*)d_in[4];
    const float* b1   = (const float*)d_in[5];
    const float* W2l  = (const float*)d_in[6];
    const float* W2r  = (const float*)d_in[7];
    const float* att2 = (const float*)d_in[8];
    const float* b2   = (const float*)d_in[9];
    const float* Wc   = (const float*)d_in[10];
    const float* bc   = (const float*)d_in[11];

    const int h1 = in_sizes[4];        // 256
    const int h2 = in_sizes[8];        // 128
    const int c  = in_sizes[11];       // 40
    const int f  = in_sizes[2] / h1;   // 128
    const int n  = in_sizes[0] / f;    // 50000
    const int E  = in_sizes[1] / 2;    // 800000
    const int Etot = E + n;

    char* p = (char*)d_ws;
    auto alloc = [&](size_t bytes) -> char* {
        char* r = p; p += (bytes + 255) & ~(size_t)255; return r;
    };
    unsigned short* xlr1 = (unsigned short*)alloc((size_t)n * 2 * h1 * 2);
    short* hsplit1 = (short*)alloc((size_t)n * 2 * h1 * 2);
    short* a2x     = (short*)alloc((size_t)n * 2 * f * 2);
    short* bt1     = (short*)alloc((size_t)(2 * h1) * (2 * f) * 2);
    short* bt2     = (short*)alloc((size_t)(2 * h2) * (2 * h1) * 2);
    short* btc     = (short*)alloc((size_t)c * (2 * h2) * 2);
    int*   csr_src = (int*)alloc((size_t)Etot * 4);
    int*   indptr  = (int*)alloc((size_t)(n + 1) * 4);
    int*   cursor  = (int*)alloc((size_t)n * 4);
    int*   deg     = (int*)alloc((size_t)n * 4);
    int*   scanned = (int*)alloc((size_t)n * 4);
    int*   sums    = (int*)alloc(4096);

    unsigned short* xlr2 = xlr1;   // alias (xlr1 dead after fused1)
    short* hsplit2 = a2x;          // alias (a2x dead after L1 GEMM)

    const int tb = 256;

    // ---- conversions ----
    long total4 = (long)n * f / 4;
    k_split_a<<<(int)((total4 + tb - 1) / tb), tb, 0, stream>>>(x, a2x, total4, f);
    k_split_bt<<<(2 * h1 * f + tb - 1) / tb, tb, 0, stream>>>(W1l, W1r, h1, h1, f, bt1);
    k_split_bt<<<(2 * h2 * h1 + tb - 1) / tb, tb, 0, stream>>>(W2l, W2r, h2, h2, h1, bt2);
    k_split_bt<<<(c * h2 + tb - 1) / tb, tb, 0, stream>>>(Wc, nullptr, c, 0, h2, btc);

    // ---- CSR build ----
    hipMemsetAsync(deg, 0, (size_t)n * 4, stream);
    k_degree<<<(Etot + tb - 1) / tb, tb, 0, stream>>>(ei, E, n, deg);
    int nb = (n + SCAN_BLK - 1) / SCAN_BLK;
    k_scan1<<<nb, SCAN_BLK, 0, stream>>>(deg, scanned, sums, n);
    k_scan2<<<1, 64, 0, stream>>>(sums, nb);
    k_scan3<<<(n + tb - 1) / tb, tb, 0, stream>>>(scanned, sums, deg, indptr, cursor, n);
    k_scatter<<<(Etot + tb - 1) / tb, tb, 0, stream>>>(ei, E, n, cursor, csr_src);

    const int gy = (n + 127) / 128;

    // ---- Layer 1: xlr1(bf16) = x @ [W1l|W1r]; fused: 2 nodes/wave (C=256) ----
    k_mfma<128, true><<<dim3((2 * h1 + 127) / 128, gy), 256, 0, stream>>>(
        a2x, bt1, nullptr, xlr1, n, 2 * h1, f);
    k_fused<2><<<(n + 7) / 8, 256, 0, stream>>>(
        xlr1, 2 * h1, h1, csr_src, indptr, att1, b1, hsplit1, n);

    // ---- Layer 2: fused: 4 nodes/wave (C=128) ----
    k_mfma<128, true><<<dim3((2 * h2 + 127) / 128, gy), 256, 0, stream>>>(
        hsplit1, bt2, nullptr, xlr2, n, 2 * h2, h1);
    k_fused<4><<<(n + 15) / 16, 256, 0, stream>>>(
        xlr2, 2 * h2, h2, csr_src, indptr, att2, b2, hsplit2, n);

    // ---- Classifier: d_out(fp32) = h2act @ Wc + bc ----
    k_mfma<64, false><<<dim3((c + 63) / 64, gy), 256, 0, stream>>>(
        hsplit2, btc, bc, d_out, n, c, h2);
}